// Round 12
// baseline (1117.682 us; speedup 1.0000x reference)
//
#include <hip/hip_runtime.h>
#include <math.h>

typedef __attribute__((ext_vector_type(8))) _Float16 f16x8;
typedef __attribute__((ext_vector_type(8))) short short8;
typedef __attribute__((ext_vector_type(4))) float f32x4;
typedef unsigned short u16;

__device__ __forceinline__ float gelu_f(float x) {
    float x3 = x * x * x;
    return 0.5f * x * (1.0f + tanhf(0.7978845608028654f * (x + 0.044715f * x3)));
}
__device__ __forceinline__ u16 f2h(float v) {
    _Float16 h = (_Float16)v;
    return *(u16*)&h;
}
__device__ __forceinline__ float h2f(u16 u) {
    _Float16 h = *(_Float16*)&u;
    return (float)h;
}

union __align__(16) SharedU {
    struct { u16 Hs[64][68]; } pr;
    struct { float tsr[128]; float red[256]; } x0;
    struct { u16 sbuf[2][2][64][32]; } gm;
    struct { u16 K16[128][72]; u16 V16[128][72]; float Ss[16 * 132]; float Qs[16][68]; } at;
    struct { float red[256]; } rl;
    struct { float xis[512]; u16 As[2][128][32]; } cr;
    struct { float G1[32][66]; float G2[32][66]; int s_src[32]; int s_dst[32]; } ef;
};

// ---------------- device-scope grid barrier (sense via generation counter) ----------------
__device__ __forceinline__ void gridbar(int* __restrict__ bar, int nb) {
    __syncthreads();
    if (threadIdx.x == 0) {
        __threadfence();                                   // release
        int* cnt = bar;
        int* gen = bar + 1;
        int g = atomicAdd(gen, 0);
        if (atomicAdd(cnt, 1) == nb - 1) {
            atomicExch(cnt, 0);
            __threadfence();
            atomicAdd(gen, 1);
        } else {
            while (atomicAdd(gen, 0) == g) { __builtin_amdgcn_s_sleep(8); }
        }
        __threadfence();                                   // acquire
    }
    __syncthreads();
}

// ---------------- weight transpose + fp16 prep (one 64x64 tile) ----------------
__device__ __forceinline__ void prep_tile(SharedU& sh, int bid,
    const float* wq, const float* wk, const float* wv,
    const float* wo, const float* w1, const float* w2, const float* ew1,
    u16* qkvt, u16* wot, u16* w1t, u16* w2t, u16* eabt, u16* ect) {
    auto& Hs = sh.pr.Hs;
    int region, tr, KK;
    u16* dh;
    if (bid < 768)       { region = 0; tr = bid;        KK = 512;  dh = qkvt; }
    else if (bid < 1024) { region = 1; tr = bid - 768;  KK = 512;  dh = wot; }
    else if (bid < 2048) { region = 2; tr = bid - 1024; KK = 512;  dh = w1t; }
    else if (bid < 3072) { region = 3; tr = bid - 2048; KK = 2048; dh = w2t; }
    else if (bid < 3088) { region = 4; tr = bid - 3072; KK = 512;  dh = eabt; }
    else                 { region = 5; tr = bid - 3088; KK = 512;  dh = ect; }
    int ktiles = KK >> 6;
    int tn = tr / ktiles, tk = tr % ktiles;
    int k0 = tk * 64, n0g = tn * 64;
    int tid = threadIdx.x;
#pragma unroll
    for (int p = 0; p < 4; ++p) {
        int kk = p * 16 + (tid >> 4);
        int nn = (tid & 15) * 4;
        int kg = k0 + kk, ng = n0g + nn;
        const float* src;
        if (region == 0) {
            int d = ng / 1536; int nr = ng - d * 1536; int sel = nr >> 9; int nc = nr & 511;
            const float* w = sel == 0 ? wq : (sel == 1 ? wk : wv);
            src = w + ((size_t)(d * 512 + kg)) * 512 + nc;
        } else if (region == 1) {
            int d = ng >> 9; int nc = ng & 511;
            src = wo + ((size_t)(d * 512 + kg)) * 512 + nc;
        } else if (region == 2) {
            int d = ng >> 11; int nc = ng & 2047;
            src = w1 + ((size_t)(d * 512 + kg)) * 2048 + nc;
        } else if (region == 3) {
            int d = ng >> 9; int nc = ng & 511;
            src = w2 + ((size_t)(d * 2048 + kg)) * 512 + nc;
        } else if (region == 4) {
            src = (ng < 64) ? (ew1 + (size_t)kg * 64 + ng) : (ew1 + (size_t)(512 + kg) * 64 + (ng - 64));
        } else {
            src = ew1 + (size_t)(1024 + kg) * 64 + ng;
        }
        float4 v = *(const float4*)src;
        *(ushort4*)&Hs[kk][nn] = make_ushort4(f2h(v.x), f2h(v.y), f2h(v.z), f2h(v.w));
    }
    __syncthreads();
#pragma unroll
    for (int p = 0; p < 2; ++p) {
        int chunk = p * 256 + tid;
        int nl = chunk >> 3;
        int k8 = (chunk & 7) * 8;
        ushort4 ha, hb;
        ha.x = Hs[k8 + 0][nl]; ha.y = Hs[k8 + 1][nl]; ha.z = Hs[k8 + 2][nl]; ha.w = Hs[k8 + 3][nl];
        hb.x = Hs[k8 + 4][nl]; hb.y = Hs[k8 + 5][nl]; hb.z = Hs[k8 + 6][nl]; hb.w = Hs[k8 + 7][nl];
        size_t dst = (size_t)(n0g + nl) * KK + k0 + k8;
        *(ushort4*)(dh + dst) = ha; *(ushort4*)(dh + dst + 4) = hb;
    }
}

// ---------------- fused tsym + x0 + LN, one row ----------------
__device__ __forceinline__ void x0row_tile(SharedU& sh, int bn,
    const float* topo, const float* weight, const float* w_topo, const float* b_topo,
    const float* w_w, const float* b_w, const float* n_emb,
    float* tsym, float* x, u16* h16) {
    auto& tsr = sh.x0.tsr;
    auto& red = sh.x0.red;
    int b = bn >> 7, n = bn & 127;
    int tid = threadIdx.x;
    if (tid < 128) {
        float v = topo[bn * 128 + tid] + topo[(b << 14) + (tid << 7) + n];
        tsr[tid] = v;
        tsym[bn * 128 + tid] = v;
    }
    __syncthreads();
    int c0 = tid, c1 = tid + 256;
    float acc0 = 0.f, acc1 = 0.f;
#pragma unroll 4
    for (int m = 0; m < 128; ++m) {
        float t = tsr[m];
        acc0 += t * w_topo[m * 512 + c0];
        acc1 += t * w_topo[m * 512 + c1];
    }
    float wgt = weight[bn];
    float v0 = acc0 + b_topo[c0] + wgt * w_w[c0] + b_w[c0] + n_emb[n * 512 + c0];
    float v1 = acc1 + b_topo[c1] + wgt * w_w[c1] + b_w[c1] + n_emb[n * 512 + c1];
    x[bn * 512 + c0] = v0;
    x[bn * 512 + c1] = v1;
    red[tid] = v0 + v1;
    __syncthreads();
    for (int off = 128; off > 0; off >>= 1) { if (tid < off) red[tid] += red[tid + off]; __syncthreads(); }
    float mean = red[0] * (1.0f / 512.0f);
    __syncthreads();
    float d0 = v0 - mean, d1 = v1 - mean;
    red[tid] = d0 * d0 + d1 * d1;
    __syncthreads();
    for (int off = 128; off > 0; off >>= 1) { if (tid < off) red[tid] += red[tid + off]; __syncthreads(); }
    float rs = rsqrtf(red[0] * (1.0f / 512.0f) + 1e-6f);
    h16[bn * 512 + c0] = f2h(d0 * rs);
    h16[bn * 512 + c1] = f2h(d1 * rs);
}

// ---------------- LDS-staged double-buffered fp16 MFMA GEMM tile ----------------
template <int KC, bool PARTIAL, bool GELU, bool RES, bool OUTF, bool OUTS, bool EBIAS>
__device__ __forceinline__ void gemm_tile(SharedU& sh, int bx, int by, int bz,
    const u16* __restrict__ A16, const u16* __restrict__ W16,
    const float* __restrict__ bias, const float* __restrict__ Rres,
    float* __restrict__ C, u16* __restrict__ C16,
    float* __restrict__ part, int lda, int N) {
    auto& sbuf = sh.gm.sbuf;
    const int tid = threadIdx.x;
    const int l = tid & 63;
    const int w = tid >> 6;
    const int bn0 = bx * 64;
    const int bm0 = by * 64;
    const int z = bz;

    const u16* gp[2];
#pragma unroll
    for (int i = 0; i < 2; ++i) {
        int o = (i * 4 + w) * 1024 + l * 16;
        int mat = o >> 12;
        int r = (o >> 6) & 63;
        int slot = (o >> 4) & 3;
        int lslot = slot ^ ((r >> 1) & 3);
        int kel = lslot * 8;
        const u16* basep = mat == 0 ? (A16 + (size_t)(bm0 + r) * lda)
                                    : (W16 + (size_t)(bn0 + r) * lda);
        gp[i] = basep + kel + z * KC;
    }

    f32x4 acc[2][2] = {};
    constexpr int S = KC / 32;

    auto stage = [&](int buf, int ko) {
#pragma unroll
        for (int i = 0; i < 2; ++i) {
            __builtin_amdgcn_global_load_lds(
                (const __attribute__((address_space(1))) void*)(gp[i] + ko),
                (__attribute__((address_space(3))) void*)((char*)&sbuf[buf][0][0][0] + (i * 4 + w) * 1024),
                16, 0, 0);
        }
    };
    auto compute = [&](int buf) {
        f16x8 a[2], b[2];
        int l15 = l & 15, lsl = l >> 4;
        int rA0 = (w & 1) * 32 + l15;
        int rB0 = (w >> 1) * 32 + l15;
#pragma unroll
        for (int f = 0; f < 2; ++f) {
            int rA = rA0 + f * 16;
            int rB = rB0 + f * 16;
            a[f] = *(const f16x8*)&sbuf[buf][0][rA][(lsl ^ ((rA >> 1) & 3)) * 8];
            b[f] = *(const f16x8*)&sbuf[buf][1][rB][(lsl ^ ((rB >> 1) & 3)) * 8];
        }
#pragma unroll
        for (int fm = 0; fm < 2; ++fm)
#pragma unroll
            for (int fn = 0; fn < 2; ++fn)
                acc[fm][fn] = __builtin_amdgcn_mfma_f32_16x16x32_f16(a[fm], b[fn], acc[fm][fn], 0, 0, 0);
    };

    stage(0, 0);
    __syncthreads();
#pragma unroll
    for (int s = 0; s < S; ++s) {
        if (s + 1 < S) stage((s + 1) & 1, (s + 1) * 32);
        compute(s & 1);
        __syncthreads();
    }

    int rb = bm0 + (w & 1) * 32 + ((l >> 4)) * 4;
    int cb = bn0 + (w >> 1) * 32 + (l & 15);
#pragma unroll
    for (int fm = 0; fm < 2; ++fm)
#pragma unroll
        for (int fn = 0; fn < 2; ++fn) {
            int col = cb + fn * 16;
            float bv;
            if (PARTIAL) bv = 0.f;
            else if (EBIAS) bv = col < 64 ? bias[col] : 0.f;
            else bv = bias[col];
#pragma unroll
            for (int r = 0; r < 4; ++r) {
                int row = rb + fm * 16 + r;
                float v = acc[fm][fn][r] + bv;
                if (PARTIAL) {
                    part[(size_t)z * 512 * N + (size_t)row * N + col] = v;
                } else {
                    if (GELU) v = gelu_f(v);
                    if (RES) v += Rres[(size_t)row * N + col];
                    if (OUTF) C[(size_t)row * N + col] = v;
                    if (OUTS) C16[(size_t)row * N + col] = f2h(v);
                }
            }
        }
}

// ---------------- split-K reduce + bias + residual -> x, then LN (or raw fp16), one row ----------------
template <int NZ, bool DOLN, bool DOSPLITX>
__device__ __forceinline__ void redln_row(SharedU& sh, int row,
    const float* __restrict__ part, const float* __restrict__ bias,
    float* __restrict__ x, u16* __restrict__ h16) {
    auto& red = sh.rl.red;
    int tid = threadIdx.x;
    int c0 = tid, c1 = tid + 256;
    float v0 = bias[c0], v1 = bias[c1];
#pragma unroll
    for (int z = 0; z < NZ; ++z) {
        v0 += part[(size_t)z * 262144 + row * 512 + c0];
        v1 += part[(size_t)z * 262144 + row * 512 + c1];
    }
    v0 += x[row * 512 + c0];
    v1 += x[row * 512 + c1];
    x[row * 512 + c0] = v0;
    x[row * 512 + c1] = v1;
    if (DOSPLITX) {
        h16[row * 512 + c0] = f2h(v0);
        h16[row * 512 + c1] = f2h(v1);
    }
    if (DOLN) {
        red[tid] = v0 + v1;
        __syncthreads();
        for (int off = 128; off > 0; off >>= 1) { if (tid < off) red[tid] += red[tid + off]; __syncthreads(); }
        float mean = red[0] * (1.0f / 512.0f);
        __syncthreads();
        float d0 = v0 - mean, d1 = v1 - mean;
        red[tid] = d0 * d0 + d1 * d1;
        __syncthreads();
        for (int off = 128; off > 0; off >>= 1) { if (tid < off) red[tid] += red[tid + off]; __syncthreads(); }
        float rs = rsqrtf(red[0] * (1.0f / 512.0f) + 1e-6f);
        h16[row * 512 + c0] = f2h(d0 * rs);
        h16[row * 512 + c1] = f2h(d1 * rs);
    }
}

// ---------------- fused masked attention tile (fp16 K/V in LDS) ----------------
__device__ __forceinline__ void attn_tile(SharedU& sh, int tt, int hh, int b,
    const float* __restrict__ pw, const float* __restrict__ bq,
    const float* __restrict__ bk, const float* __restrict__ bv,
    const float* __restrict__ tsym, u16* __restrict__ agg16) {
    auto& K16 = sh.at.K16;
    auto& V16 = sh.at.V16;
    float* Ss = sh.at.Ss;
    auto& Qs = sh.at.Qs;
    int tid = threadIdx.x;
    {
        int j = tid >> 1, c0 = (tid & 1) * 32;
        const float* kr0 = pw + (size_t)(b * 128 + j) * 1536 + 512 + hh * 64 + c0;
        const float* kr1 = kr0 + 786432;
        const float* bkp = bk + hh * 64 + c0;
        const float* bvp = bv + hh * 64 + c0;
#pragma unroll
        for (int c = 0; c < 32; c += 4) {
            float4 k0v = *(const float4*)(kr0 + c);
            float4 k1v = *(const float4*)(kr1 + c);
            float4 v0v = *(const float4*)(kr0 + 512 + c);
            float4 v1v = *(const float4*)(kr1 + 512 + c);
            float4 bkv = *(const float4*)(bkp + c);
            float4 bvv = *(const float4*)(bvp + c);
            K16[j][c0 + c + 0] = f2h(k0v.x + k1v.x + bkv.x);
            K16[j][c0 + c + 1] = f2h(k0v.y + k1v.y + bkv.y);
            K16[j][c0 + c + 2] = f2h(k0v.z + k1v.z + bkv.z);
            K16[j][c0 + c + 3] = f2h(k0v.w + k1v.w + bkv.w);
            V16[j][c0 + c + 0] = f2h(v0v.x + v1v.x + bvv.x);
            V16[j][c0 + c + 1] = f2h(v0v.y + v1v.y + bvv.y);
            V16[j][c0 + c + 2] = f2h(v0v.z + v1v.z + bvv.z);
            V16[j][c0 + c + 3] = f2h(v0v.w + v1v.w + bvv.w);
        }
    }
    {
        int rid = tid >> 4, c4 = (tid & 15) * 4;
        int grow = b * 128 + tt * 16 + rid;
        const float* q0 = pw + (size_t)grow * 1536 + hh * 64 + c4;
        float4 a = *(const float4*)q0;
        float4 a1 = *(const float4*)(q0 + 786432);
        float4 bb = *(const float4*)(bq + hh * 64 + c4);
        Qs[rid][c4 + 0] = a.x + a1.x + bb.x;
        Qs[rid][c4 + 1] = a.y + a1.y + bb.y;
        Qs[rid][c4 + 2] = a.z + a1.z + bb.z;
        Qs[rid][c4 + 3] = a.w + a1.w + bb.w;
    }
    __syncthreads();
    {
        int j = tid & 127, th = tid >> 7;
        float acc[8] = {0.f, 0.f, 0.f, 0.f, 0.f, 0.f, 0.f, 0.f};
        for (int d0 = 0; d0 < 64; d0 += 8) {
            f16x8 kv = *(const f16x8*)&K16[j][d0];
            float kf[8];
#pragma unroll
            for (int q = 0; q < 8; ++q) kf[q] = (float)kv[q];
#pragma unroll
            for (int r = 0; r < 8; ++r) {
                const float* qp = &Qs[th * 8 + r][d0];
                acc[r] += qp[0] * kf[0] + qp[1] * kf[1] + qp[2] * kf[2] + qp[3] * kf[3]
                        + qp[4] * kf[4] + qp[5] * kf[5] + qp[6] * kf[6] + qp[7] * kf[7];
            }
        }
        const float* tsr = tsym + ((size_t)b << 14) + (size_t)(tt * 16 + th * 8) * 128 + j;
#pragma unroll
        for (int r = 0; r < 8; ++r) {
            int t = th * 8 + r;
            float sv = (tsr[r * 128] > 0.f) ? acc[r] * 0.125f : -INFINITY;
            Ss[t * 132 + j] = sv;
        }
    }
    __syncthreads();
    {
        int row = tid >> 4, l16 = tid & 15;
        float v[8]; float m = -INFINITY;
#pragma unroll
        for (int c = 0; c < 8; ++c) { v[c] = Ss[row * 132 + l16 + c * 16]; m = fmaxf(m, v[c]); }
#pragma unroll
        for (int off = 8; off; off >>= 1) m = fmaxf(m, __shfl_xor(m, off));
        float ssum = 0.f;
#pragma unroll
        for (int c = 0; c < 8; ++c) {
            float e = (v[c] == -INFINITY) ? 0.f : __expf(v[c] - m);
            v[c] = e; ssum += e;
        }
#pragma unroll
        for (int off = 8; off; off >>= 1) ssum += __shfl_xor(ssum, off);
        float inv = 1.0f / (ssum + 1e-12f);
#pragma unroll
        for (int c = 0; c < 8; ++c) Ss[row * 132 + l16 + c * 16] = v[c] * inv;
    }
    __syncthreads();
    {
        int d = tid & 63, tq = tid >> 6;
        float a0 = 0.f, a1 = 0.f, a2 = 0.f, a3 = 0.f;
        const float* s0p = &Ss[(tq * 4 + 0) * 132];
        const float* s1p = &Ss[(tq * 4 + 1) * 132];
        const float* s2p = &Ss[(tq * 4 + 2) * 132];
        const float* s3p = &Ss[(tq * 4 + 3) * 132];
        for (int j0 = 0; j0 < 128; ++j0) {
            float vv = h2f(V16[j0][d]);
            a0 += s0p[j0] * vv;
            a1 += s1p[j0] * vv;
            a2 += s2p[j0] * vv;
            a3 += s3p[j0] * vv;
        }
        float accv[4] = {a0, a1, a2, a3};
        int growbase = b * 128 + tt * 16;
#pragma unroll
        for (int i = 0; i < 4; ++i) {
            int t = tq * 4 + i;
            agg16[(size_t)(growbase + t) * 512 + hh * 64 + d] = f2h(accv[i]);
        }
    }
}

// ---------------- dense cross-term GEMM tile ----------------
__device__ __forceinline__ void cross_tile(SharedU& sh, int i, int b,
    const float* __restrict__ x, const u16* __restrict__ ect, float* __restrict__ C3) {
    auto& xis = sh.cr.xis;
    auto& As = sh.cr.As;
    int tid = threadIdx.x;
    {
        const float* xip = x + (size_t)(b * 128 + i) * 512;
        xis[tid] = xip[tid];
        xis[tid + 256] = xip[tid + 256];
    }
    int r = tid >> 1, half = tid & 1, koff = half * 16;
    const float* xr = x + (size_t)(b * 128 + r) * 512 + koff;
    int sw_r = (r >> 1) & 3;
    int lane = tid & 63, w = tid >> 6;
    int m0 = (w & 1) * 64, n0 = (w >> 1) * 32;
    int l15 = lane & 15, lsl = lane >> 4, kf = lsl * 8;
    const u16* pB0 = ect + (size_t)(n0 + l15) * 512 + kf;
    const u16* pB1 = ect + (size_t)(n0 + 16 + l15) * 512 + kf;
    f32x4 acc[4][2] = {};

    auto stageA = [&](int buf, int kbase) {
        float4 v0 = *(const float4*)(xr + kbase);
        float4 v1 = *(const float4*)(xr + kbase + 4);
        float4 v2 = *(const float4*)(xr + kbase + 8);
        float4 v3 = *(const float4*)(xr + kbase + 12);
        float xv[16] = {v0.x, v0.y, v0.z, v0.w, v1.x, v1.y, v1.z, v1.w,
                        v2.x, v2.y, v2.z, v2.w, v3.x, v3.y, v3.z, v3.w};
        short8 h0, h1;
#pragma unroll
        for (int q = 0; q < 8; ++q)
            h0[q] = (short)f2h(xv[q] * xis[kbase + koff + q]);
#pragma unroll
        for (int q = 0; q < 8; ++q)
            h1[q] = (short)f2h(xv[8 + q] * xis[kbase + koff + 8 + q]);
        *(short8*)&As[buf][r][((2 * half + 0) ^ sw_r) * 8] = h0;
        *(short8*)&As[buf][r][((2 * half + 1) ^ sw_r) * 8] = h1;
    };
    auto computeC = [&](int buf, int kbase) {
        f16x8 b0 = *(const f16x8*)(pB0 + kbase);
        f16x8 b1 = *(const f16x8*)(pB1 + kbase);
#pragma unroll
        for (int mf = 0; mf < 4; ++mf) {
            int rA = m0 + mf * 16 + l15;
            f16x8 ah = *(const f16x8*)&As[buf][rA][(lsl ^ ((rA >> 1) & 3)) * 8];
            acc[mf][0] = __builtin_amdgcn_mfma_f32_16x16x32_f16(ah, b0, acc[mf][0], 0, 0, 0);
            acc[mf][1] = __builtin_amdgcn_mfma_f32_16x16x32_f16(ah, b1, acc[mf][1], 0, 0, 0);
        }
    };

    __syncthreads();
    stageA(0, 0);
    __syncthreads();
    for (int s = 0; s < 16; ++s) {
        if (s < 15) stageA((s + 1) & 1, (s + 1) * 32);
        computeC(s & 1, s * 32);
        __syncthreads();
    }

    float* outp = C3 + (size_t)(b * 128 + i) * 128 * 64;
#pragma unroll
    for (int mf = 0; mf < 4; ++mf)
#pragma unroll
        for (int nf = 0; nf < 2; ++nf)
#pragma unroll
            for (int q = 0; q < 4; ++q)
                outp[(size_t)(m0 + mf * 16 + lsl * 4 + q) * 64 + (n0 + nf * 16 + l15)] = acc[mf][nf][q];
}

// ---------------- per-edge finish (fused aebe 4-slice reduce) ----------------
__device__ __forceinline__ void efin_tile(SharedU& sh, int blk,
    const int* __restrict__ ei, int E,
    const float* __restrict__ C3, const float* __restrict__ pw, const float* __restrict__ eb1,
    const float* __restrict__ ew2, const float* __restrict__ eb2,
    const float* __restrict__ ew3, const float* __restrict__ eb3,
    float* __restrict__ P) {
    auto& G1 = sh.ef.G1;
    auto& G2 = sh.ef.G2;
    auto& s_src = sh.ef.s_src;
    auto& s_dst = sh.ef.s_dst;
    int tid = threadIdx.x;
    int e0 = blk * 32;
    if (tid < 32) {
        int e = e0 + tid;
        s_src[tid] = e < E ? ei[e] : 0;
        s_dst[tid] = e < E ? ei[E + e] : 0;
    }
    __syncthreads();
    {
        int e = tid >> 3, c8 = (tid & 7) * 8;
        int s = s_src[e], d = s_dst[e];
        int bB = s >> 7, i2 = s & 127, j2 = d & 127;
        const float* c3 = C3 + ((size_t)(bB * 128 + i2) * 128 + j2) * 64 + c8;
#pragma unroll
        for (int q = 0; q < 8; ++q) {
            int col = c8 + q;
            float av = eb1[col];
            float bv = 0.f;
#pragma unroll
            for (int z = 0; z < 4; ++z) {
                av += pw[(size_t)z * 65536 + s * 128 + col];
                bv += pw[(size_t)z * 65536 + d * 128 + 64 + col];
            }
            G1[e][col] = gelu_f(c3[q] + av + bv);
        }
    }
    __syncthreads();
    {
        int col = tid & 63, eq = tid >> 6;
        float acc[8];
#pragma unroll
        for (int i = 0; i < 8; ++i) acc[i] = eb2[col];
        for (int m = 0; m < 64; ++m) {
            float wv = ew2[m * 64 + col];
#pragma unroll
            for (int i = 0; i < 8; ++i) acc[i] += G1[eq * 8 + i][m] * wv;
        }
#pragma unroll
        for (int i = 0; i < 8; ++i) G2[eq * 8 + i][col] = gelu_f(acc[i]);
    }
    __syncthreads();
    {
        int el2 = tid >> 3, c8 = (tid & 7) * 8;
        float p = 0.f;
#pragma unroll
        for (int i = 0; i < 8; ++i) p += G2[el2][c8 + i] * ew3[c8 + i];
        p += __shfl_xor(p, 1); p += __shfl_xor(p, 2); p += __shfl_xor(p, 4);
        if ((tid & 7) == 0 && e0 + el2 < E) {
            float logit = p + eb3[0];
            int s = s_src[el2], d2 = s_dst[el2];
            int bB = s >> 7, i2 = s & 127, j2 = d2 & 127;
            P[(bB << 14) + (i2 << 7) + j2] = 1.0f / (1.0f + expf(-logit));
        }
    }
}

// ---------------- final symmetrize + mask (one 256-elem chunk) ----------------
__device__ __forceinline__ void final_tile(int t, const float* __restrict__ tsym,
                                           const float* __restrict__ P, float* __restrict__ out) {
    int idx = t * 256 + threadIdx.x;
    int b = idx >> 14, i = (idx >> 7) & 127, j = idx & 127;
    float o = 0.0f;
    if (i != j && tsym[idx] > 0.0f)
        o = 0.5f * (P[idx] + P[(b << 14) + (j << 7) + i]);
    out[idx] = o;
}

// ---------------- the mega kernel ----------------
struct MegaP {
    const float* topo; const float* weight; const int* ei;
    const float* w_topo; const float* b_topo; const float* w_w; const float* b_w; const float* n_emb;
    const float* wq; const float* bq; const float* wk; const float* bk;
    const float* wv; const float* bv; const float* wo; const float* bo;
    const float* w1; const float* b1; const float* w2; const float* b2;
    const float* ew1; const float* eb1; const float* ew2; const float* eb2;
    const float* ew3; const float* eb3;
    u16* qkvt; u16* wot; u16* w1t; u16* w2t; u16* eabt; u16* ect;
    u16* h16; u16* agg16; u16* mid16; u16* x16;
    float* tsym; float* x; float* pw; float* C3; float* P; float* out;
    int* bar;
    int E;
};

__global__ __launch_bounds__(256, 1) void mega(MegaP p) {
    __shared__ SharedU sh;
    const int bid = blockIdx.x;
    const int nb = gridDim.x;

    for (int t = bid; t < 3096; t += nb) {
        prep_tile(sh, t, p.wq, p.wk, p.wv, p.wo, p.w1, p.w2, p.ew1,
                  p.qkvt, p.wot, p.w1t, p.w2t, p.eabt, p.ect);
        __syncthreads();
    }
    for (int t = bid; t < 512; t += nb) {
        x0row_tile(sh, t, p.topo, p.weight, p.w_topo, p.b_topo, p.w_w, p.b_w, p.n_emb,
                   p.tsym, p.x, p.h16);
        __syncthreads();
    }
    gridbar(p.bar, nb);

    for (int d = 0; d < 4; ++d) {
        const u16* qk = p.qkvt + (size_t)d * 1536 * 512;
        for (int t = bid; t < 384; t += nb) {
            gemm_tile<256, true, false, false, false, false, false>(sh, t % 24, (t / 24) & 7, t / 192,
                p.h16, qk, nullptr, nullptr, nullptr, nullptr, p.pw, 512, 1536);
            __syncthreads();
        }
        gridbar(p.bar, nb);
        for (int t = bid; t < 256; t += nb) {
            attn_tile(sh, t & 7, (t >> 3) & 7, t >> 6,
                      p.pw, p.bq + d * 512, p.bk + d * 512, p.bv + d * 512, p.tsym, p.agg16);
            __syncthreads();
        }
        gridbar(p.bar, nb);
        const u16* wod = p.wot + (size_t)d * 512 * 512;
        for (int t = bid; t < 256; t += nb) {
            gemm_tile<128, true, false, false, false, false, false>(sh, t & 7, (t >> 3) & 7, t >> 6,
                p.agg16, wod, nullptr, nullptr, nullptr, nullptr, p.pw, 512, 512);
            __syncthreads();
        }
        gridbar(p.bar, nb);
        for (int t = bid; t < 512; t += nb) {
            redln_row<4, true, false>(sh, t, p.pw, p.bo + d * 512, p.x, p.h16);
            __syncthreads();
        }
        gridbar(p.bar, nb);
        const u16* w1d = p.w1t + (size_t)d * 2048 * 512;
        for (int t = bid; t < 256; t += nb) {
            gemm_tile<512, false, true, false, false, true, false>(sh, t & 31, t >> 5, 0,
                p.h16, w1d, p.b1 + d * 2048, nullptr, nullptr, p.mid16, nullptr, 512, 2048);
            __syncthreads();
        }
        gridbar(p.bar, nb);
        const u16* w2d = p.w2t + (size_t)d * 512 * 2048;
        for (int t = bid; t < 256; t += nb) {
            gemm_tile<512, true, false, false, false, false, false>(sh, t & 7, (t >> 3) & 7, t >> 6,
                p.mid16, w2d, nullptr, nullptr, nullptr, nullptr, p.pw, 2048, 512);
            __syncthreads();
        }
        gridbar(p.bar, nb);
        if (d < 3) {
            for (int t = bid; t < 512; t += nb) {
                redln_row<4, true, false>(sh, t, p.pw, p.b2 + d * 512, p.x, p.h16);
                __syncthreads();
            }
        } else {
            for (int t = bid; t < 512; t += nb) {
                redln_row<4, false, true>(sh, t, p.pw, p.b2 + d * 512, p.x, p.x16);
                __syncthreads();
            }
        }
        gridbar(p.bar, nb);
    }

    for (int t = bid; t < 576; t += nb) {
        if (t < 64) {
            gemm_tile<128, true, false, false, false, false, false>(sh, t & 1, (t >> 1) & 7, t >> 4,
                p.x16, p.eabt, nullptr, nullptr, nullptr, nullptr, p.pw, 512, 128);
        } else {
            int u = t - 64;
            cross_tile(sh, u & 127, u >> 7, p.x, p.ect, p.C3);
        }
        __syncthreads();
    }
    gridbar(p.bar, nb);
    int nE = (p.E + 31) >> 5;
    for (int t = bid; t < nE; t += nb) {
        efin_tile(sh, t, p.ei, p.E, p.C3, p.pw, p.eb1, p.ew2, p.eb2, p.ew3, p.eb3, p.P);
        __syncthreads();
    }
    gridbar(p.bar, nb);
    for (int t = bid; t < 256; t += nb) {
        final_tile(t, p.tsym, p.P, p.out);
    }
}

extern "C" void kernel_launch(void* const* d_in, const int* in_sizes, int n_in,
                              void* d_out, int out_size, void* d_ws, size_t ws_size,
                              hipStream_t stream) {
    char* base = (char*)d_ws;
    size_t off = 0;
    auto alloc = [&](size_t bytes) { char* pp = base + off; off += (bytes + 255) & ~(size_t)255; return pp; };

    MegaP p;
    p.topo   = (const float*)d_in[0];
    p.weight = (const float*)d_in[1];
    p.ei     = (const int*)d_in[2];
    p.w_topo = (const float*)d_in[3];
    p.b_topo = (const float*)d_in[4];
    p.w_w    = (const float*)d_in[5];
    p.b_w    = (const float*)d_in[6];
    p.n_emb  = (const float*)d_in[7];
    p.wq = (const float*)d_in[8];  p.bq = (const float*)d_in[9];
    p.wk = (const float*)d_in[10]; p.bk = (const float*)d_in[11];
    p.wv = (const float*)d_in[12]; p.bv = (const float*)d_in[13];
    p.wo = (const float*)d_in[14]; p.bo = (const float*)d_in[15];
    p.w1 = (const float*)d_in[16]; p.b1 = (const float*)d_in[17];
    p.w2 = (const float*)d_in[18]; p.b2 = (const float*)d_in[19];
    p.ew1 = (const float*)d_in[20]; p.eb1 = (const float*)d_in[21];
    p.ew2 = (const float*)d_in[22]; p.eb2 = (const float*)d_in[23];
    p.ew3 = (const float*)d_in[24]; p.eb3 = (const float*)d_in[25];
    p.E = in_sizes[2] / 2;

    p.qkvt  = (u16*)alloc(3145728 * 2);
    p.wot   = (u16*)alloc(1048576 * 2);
    p.w1t   = (u16*)alloc(4194304 * 2);
    p.w2t   = (u16*)alloc(4194304 * 2);
    p.eabt  = (u16*)alloc(65536 * 2);
    p.ect   = (u16*)alloc(32768 * 2);
    p.h16   = (u16*)alloc(262144 * 2);
    p.agg16 = (u16*)alloc(262144 * 2);
    p.mid16 = (u16*)alloc(1048576 * 2);
    p.x16   = (u16*)alloc(262144 * 2);
    p.tsym  = (float*)alloc(65536 * 4);
    p.x     = (float*)alloc(262144 * 4);
    p.pw    = (float*)alloc(1572864 * 4);
    p.C3    = (float*)alloc((size_t)16777216 * 4);
    p.P     = (float*)alloc(65536 * 4);
    p.bar   = (int*)alloc(256);
    p.out   = (float*)d_out;

    // barrier state must be zero at kernel start every call (ws is poisoned 0xAA once)
    hipMemsetAsync(p.bar, 0, 8, stream);

    void* args[] = { &p };
    hipError_t err = hipLaunchCooperativeKernel((const void*)mega, dim3(256), dim3(256), args, 0, stream);
    if (err != hipSuccess) {
        // same kernel, plain launch: barrier is self-implemented, co-residency holds
        // (49.7 KB LDS, 1 block/CU floor, grid == CU count)
        mega<<<dim3(256), dim3(256), 0, stream>>>(p);
    }
}

// Round 13
// 447.733 us; speedup vs baseline: 2.4963x; 2.4963x over previous
//
#include <hip/hip_runtime.h>
#include <hip/hip_bf16.h>
#include <math.h>

typedef __attribute__((ext_vector_type(8))) _Float16 f16x8;
typedef __attribute__((ext_vector_type(8))) short short8;
typedef __attribute__((ext_vector_type(4))) float f32x4;
typedef unsigned short u16;

__device__ __forceinline__ float gelu_f(float x) {
    float x3 = x * x * x;
    return 0.5f * x * (1.0f + tanhf(0.7978845608028654f * (x + 0.044715f * x3)));
}
__device__ __forceinline__ u16 f2h(float v) {
    _Float16 h = (_Float16)v;
    return *(u16*)&h;
}

// ---------------- fused tsym + x0 + LN (+ tsym store), one row per block ----------------
__global__ __launch_bounds__(256) void x0row_k(const float* __restrict__ topo,
                                               const float* __restrict__ weight,
                                               const float* __restrict__ w_topo,
                                               const float* __restrict__ b_topo,
                                               const float* __restrict__ w_w,
                                               const float* __restrict__ b_w,
                                               const float* __restrict__ n_emb,
                                               float* __restrict__ tsym,
                                               float* __restrict__ x,
                                               u16* __restrict__ h16) {
    int bn = blockIdx.x;                 // 0..511
    int b = bn >> 7, n = bn & 127;
    int tid = threadIdx.x;
    __shared__ float tsr[128];
    __shared__ float red[256];
    if (tid < 128) {
        float v = topo[bn * 128 + tid] + topo[(b << 14) + (tid << 7) + n];
        tsr[tid] = v;
        tsym[bn * 128 + tid] = v;
    }
    __syncthreads();
    int c0 = tid, c1 = tid + 256;
    float acc0 = 0.f, acc1 = 0.f;
#pragma unroll 4
    for (int m = 0; m < 128; ++m) {
        float t = tsr[m];
        acc0 += t * w_topo[m * 512 + c0];
        acc1 += t * w_topo[m * 512 + c1];
    }
    float wgt = weight[bn];
    float v0 = acc0 + b_topo[c0] + wgt * w_w[c0] + b_w[c0] + n_emb[n * 512 + c0];
    float v1 = acc1 + b_topo[c1] + wgt * w_w[c1] + b_w[c1] + n_emb[n * 512 + c1];
    x[bn * 512 + c0] = v0;
    x[bn * 512 + c1] = v1;
    red[tid] = v0 + v1;
    __syncthreads();
    for (int off = 128; off > 0; off >>= 1) { if (tid < off) red[tid] += red[tid + off]; __syncthreads(); }
    float mean = red[0] * (1.0f / 512.0f);
    __syncthreads();
    float d0 = v0 - mean, d1 = v1 - mean;
    red[tid] = d0 * d0 + d1 * d1;
    __syncthreads();
    for (int off = 128; off > 0; off >>= 1) { if (tid < off) red[tid] += red[tid + off]; __syncthreads(); }
    float rs = rsqrtf(red[0] * (1.0f / 512.0f) + 1e-6f);
    h16[bn * 512 + c0] = f2h(d0 * rs);
    h16[bn * 512 + c1] = f2h(d1 * rs);
}

// ---------------- weight transpose + fp16 prep ----------------
__global__ __launch_bounds__(256) void prep_k(
    const float* __restrict__ wq, const float* __restrict__ wk, const float* __restrict__ wv,
    const float* __restrict__ wo, const float* __restrict__ w1, const float* __restrict__ w2,
    const float* __restrict__ ew1,
    u16* __restrict__ qkvt, u16* __restrict__ wot,
    u16* __restrict__ w1t, u16* __restrict__ w2t,
    u16* __restrict__ eabt, u16* __restrict__ ect) {
    __shared__ u16 Hs[64][68];
    int bid = blockIdx.x;
    int region, tr, KK;
    u16* dh;
    if (bid < 768)       { region = 0; tr = bid;        KK = 512;  dh = qkvt; }
    else if (bid < 1024) { region = 1; tr = bid - 768;  KK = 512;  dh = wot; }
    else if (bid < 2048) { region = 2; tr = bid - 1024; KK = 512;  dh = w1t; }
    else if (bid < 3072) { region = 3; tr = bid - 2048; KK = 2048; dh = w2t; }
    else if (bid < 3088) { region = 4; tr = bid - 3072; KK = 512;  dh = eabt; }
    else                 { region = 5; tr = bid - 3088; KK = 512;  dh = ect; }
    int ktiles = KK >> 6;
    int tn = tr / ktiles, tk = tr % ktiles;
    int k0 = tk * 64, n0g = tn * 64;
    int tid = threadIdx.x;
#pragma unroll
    for (int p = 0; p < 4; ++p) {
        int kk = p * 16 + (tid >> 4);
        int nn = (tid & 15) * 4;
        int kg = k0 + kk, ng = n0g + nn;
        const float* src;
        if (region == 0) {
            int d = ng / 1536; int nr = ng - d * 1536; int sel = nr >> 9; int nc = nr & 511;
            const float* w = sel == 0 ? wq : (sel == 1 ? wk : wv);
            src = w + ((size_t)(d * 512 + kg)) * 512 + nc;
        } else if (region == 1) {
            int d = ng >> 9; int nc = ng & 511;
            src = wo + ((size_t)(d * 512 + kg)) * 512 + nc;
        } else if (region == 2) {
            int d = ng >> 11; int nc = ng & 2047;
            src = w1 + ((size_t)(d * 512 + kg)) * 2048 + nc;
        } else if (region == 3) {
            int d = ng >> 9; int nc = ng & 511;
            src = w2 + ((size_t)(d * 2048 + kg)) * 512 + nc;
        } else if (region == 4) {
            src = (ng < 64) ? (ew1 + (size_t)kg * 64 + ng) : (ew1 + (size_t)(512 + kg) * 64 + (ng - 64));
        } else {
            src = ew1 + (size_t)(1024 + kg) * 64 + ng;
        }
        float4 v = *(const float4*)src;
        *(ushort4*)&Hs[kk][nn] = make_ushort4(f2h(v.x), f2h(v.y), f2h(v.z), f2h(v.w));
    }
    __syncthreads();
#pragma unroll
    for (int p = 0; p < 2; ++p) {
        int chunk = p * 256 + tid;
        int nl = chunk >> 3;
        int k8 = (chunk & 7) * 8;
        ushort4 ha, hb;
        ha.x = Hs[k8 + 0][nl]; ha.y = Hs[k8 + 1][nl]; ha.z = Hs[k8 + 2][nl]; ha.w = Hs[k8 + 3][nl];
        hb.x = Hs[k8 + 4][nl]; hb.y = Hs[k8 + 5][nl]; hb.z = Hs[k8 + 6][nl]; hb.w = Hs[k8 + 7][nl];
        size_t dst = (size_t)(n0g + nl) * KK + k0 + k8;
        *(ushort4*)(dh + dst) = ha; *(ushort4*)(dh + dst + 4) = hb;
    }
}

// ---------------- LDS-staged double-buffered fp16 MFMA GEMM ----------------
template <int KC, bool PARTIAL, bool GELU, bool RES, bool OUTF, bool OUTS, bool EBIAS>
__global__ __launch_bounds__(256) void gemm2(
    const u16* __restrict__ A16, const u16* __restrict__ W16,
    const float* __restrict__ bias, const float* __restrict__ Rres,
    float* __restrict__ C, u16* __restrict__ C16,
    float* __restrict__ part, int lda, int N) {
    __shared__ u16 sbuf[2][2][64][32];  // [buf][A/B][row][32 fp16]
    const int tid = threadIdx.x;
    const int l = tid & 63;
    const int w = tid >> 6;
    const int bn0 = blockIdx.x * 64;
    const int bm0 = blockIdx.y * 64;
    const int z = blockIdx.z;

    const u16* gp[2];
#pragma unroll
    for (int i = 0; i < 2; ++i) {
        int o = (i * 4 + w) * 1024 + l * 16;
        int mat = o >> 12;               // 0 = A, 1 = B
        int r = (o >> 6) & 63;
        int slot = (o >> 4) & 3;
        int lslot = slot ^ ((r >> 1) & 3);
        int kel = lslot * 8;
        const u16* basep = mat == 0 ? (A16 + (size_t)(bm0 + r) * lda)
                                    : (W16 + (size_t)(bn0 + r) * lda);
        gp[i] = basep + kel + z * KC;
    }

    f32x4 acc[2][2] = {};
    constexpr int S = KC / 32;

    auto stage = [&](int buf, int ko) {
#pragma unroll
        for (int i = 0; i < 2; ++i) {
            __builtin_amdgcn_global_load_lds(
                (const __attribute__((address_space(1))) void*)(gp[i] + ko),
                (__attribute__((address_space(3))) void*)((char*)&sbuf[buf][0][0][0] + (i * 4 + w) * 1024),
                16, 0, 0);
        }
    };
    auto compute = [&](int buf) {
        f16x8 a[2], b[2];
        int l15 = l & 15, lsl = l >> 4;
        int rA0 = (w & 1) * 32 + l15;
        int rB0 = (w >> 1) * 32 + l15;
#pragma unroll
        for (int f = 0; f < 2; ++f) {
            int rA = rA0 + f * 16;
            int rB = rB0 + f * 16;
            a[f] = *(const f16x8*)&sbuf[buf][0][rA][(lsl ^ ((rA >> 1) & 3)) * 8];
            b[f] = *(const f16x8*)&sbuf[buf][1][rB][(lsl ^ ((rB >> 1) & 3)) * 8];
        }
#pragma unroll
        for (int fm = 0; fm < 2; ++fm)
#pragma unroll
            for (int fn = 0; fn < 2; ++fn)
                acc[fm][fn] = __builtin_amdgcn_mfma_f32_16x16x32_f16(a[fm], b[fn], acc[fm][fn], 0, 0, 0);
    };

    stage(0, 0);
    __syncthreads();
#pragma unroll
    for (int s = 0; s < S; ++s) {
        if (s + 1 < S) stage((s + 1) & 1, (s + 1) * 32);
        compute(s & 1);
        __syncthreads();
    }

    int rb = bm0 + (w & 1) * 32 + ((l >> 4)) * 4;
    int cb = bn0 + (w >> 1) * 32 + (l & 15);
#pragma unroll
    for (int fm = 0; fm < 2; ++fm)
#pragma unroll
        for (int fn = 0; fn < 2; ++fn) {
            int col = cb + fn * 16;
            float bv;
            if (PARTIAL) bv = 0.f;
            else if (EBIAS) bv = col < 64 ? bias[col] : 0.f;
            else bv = bias[col];
#pragma unroll
            for (int r = 0; r < 4; ++r) {
                int row = rb + fm * 16 + r;
                float v = acc[fm][fn][r] + bv;
                if (PARTIAL) {
                    part[(size_t)z * 512 * N + (size_t)row * N + col] = v;
                } else {
                    if (GELU) v = gelu_f(v);
                    if (RES) v += Rres[(size_t)row * N + col];
                    if (OUTF) C[(size_t)row * N + col] = v;
                    if (OUTS) C16[(size_t)row * N + col] = f2h(v);
                }
            }
        }
}

// ---------------- split-K reduce + bias + residual -> x, then LN (or raw fp16) ----------------
template <int NZ, bool DOLN, bool DOSPLITX>
__global__ __launch_bounds__(256) void redln_k(const float* __restrict__ part,
                                               const float* __restrict__ bias,
                                               float* __restrict__ x,
                                               u16* __restrict__ h16) {
    int row = blockIdx.x;
    int tid = threadIdx.x;
    int c0 = tid, c1 = tid + 256;
    float v0 = bias[c0], v1 = bias[c1];
#pragma unroll
    for (int z = 0; z < NZ; ++z) {
        v0 += part[(size_t)z * 262144 + row * 512 + c0];
        v1 += part[(size_t)z * 262144 + row * 512 + c1];
    }
    v0 += x[row * 512 + c0];
    v1 += x[row * 512 + c1];
    x[row * 512 + c0] = v0;
    x[row * 512 + c1] = v1;
    if (DOSPLITX) {
        h16[row * 512 + c0] = f2h(v0);
        h16[row * 512 + c1] = f2h(v1);
    }
    if (DOLN) {
        __shared__ float red[256];
        red[tid] = v0 + v1;
        __syncthreads();
        for (int off = 128; off > 0; off >>= 1) { if (tid < off) red[tid] += red[tid + off]; __syncthreads(); }
        float mean = red[0] * (1.0f / 512.0f);
        __syncthreads();
        float d0 = v0 - mean, d1 = v1 - mean;
        red[tid] = d0 * d0 + d1 * d1;
        __syncthreads();
        for (int off = 128; off > 0; off >>= 1) { if (tid < off) red[tid] += red[tid + off]; __syncthreads(); }
        float rs = rsqrtf(red[0] * (1.0f / 512.0f) + 1e-6f);
        h16[row * 512 + c0] = f2h(d0 * rs);
        h16[row * 512 + c1] = f2h(d1 * rs);
    }
}

// ---------------- mlp1 split-K reduce + bias + gelu -> mid16, one row (2048 cols) ----------------
__global__ __launch_bounds__(256) void redg_k(const float* __restrict__ part,
                                              const float* __restrict__ bias,
                                              u16* __restrict__ mid16) {
    int row = blockIdx.x;
    int tid = threadIdx.x;
#pragma unroll
    for (int u = 0; u < 8; ++u) {
        int col = tid + u * 256;
        float v = bias[col] + part[(size_t)row * 2048 + col]
                + part[(size_t)1048576 + row * 2048 + col];
        mid16[(size_t)row * 2048 + col] = f2h(gelu_f(v));
    }
}

// ---------------- fused masked attention; reads 4 QKV split-K partials + biases ----------------
__global__ __launch_bounds__(256) void attn_k(const float* __restrict__ pw,
                                              const float* __restrict__ bq,
                                              const float* __restrict__ bk,
                                              const float* __restrict__ bv,
                                              const float* __restrict__ tsym,
                                              u16* __restrict__ agg16) {
    int tt = blockIdx.x, hh = blockIdx.y, b = blockIdx.z;
    __shared__ __align__(16) float Ks[128 * 68];
    __shared__ __align__(16) float Vt[64 * 132];
    __shared__ __align__(16) float Ss[16 * 132];
    __shared__ __align__(16) float Qs[16][68];
    int tid = threadIdx.x;
    {
        int j = tid >> 1, c0 = (tid & 1) * 32;
        const float* kr0 = pw + (size_t)(b * 128 + j) * 1536 + 512 + hh * 64 + c0;
        const float* bkp = bk + hh * 64 + c0;
        const float* bvp = bv + hh * 64 + c0;
#pragma unroll
        for (int c = 0; c < 32; c += 4) {
            float4 bkv = *(const float4*)(bkp + c);
            float4 bvv = *(const float4*)(bvp + c);
            float k0 = bkv.x, k1 = bkv.y, k2 = bkv.z, k3 = bkv.w;
            float v0 = bvv.x, v1 = bvv.y, v2 = bvv.z, v3 = bvv.w;
#pragma unroll
            for (int z = 0; z < 4; ++z) {
                float4 kv = *(const float4*)(kr0 + (size_t)z * 786432 + c);
                float4 vv = *(const float4*)(kr0 + (size_t)z * 786432 + 512 + c);
                k0 += kv.x; k1 += kv.y; k2 += kv.z; k3 += kv.w;
                v0 += vv.x; v1 += vv.y; v2 += vv.z; v3 += vv.w;
            }
            Ks[j * 68 + c0 + c + 0] = k0; Ks[j * 68 + c0 + c + 1] = k1;
            Ks[j * 68 + c0 + c + 2] = k2; Ks[j * 68 + c0 + c + 3] = k3;
            Vt[(c0 + c + 0) * 132 + j] = v0; Vt[(c0 + c + 1) * 132 + j] = v1;
            Vt[(c0 + c + 2) * 132 + j] = v2; Vt[(c0 + c + 3) * 132 + j] = v3;
        }
    }
    {
        int rid = tid >> 4, c4 = (tid & 15) * 4;
        int grow = b * 128 + tt * 16 + rid;
        const float* q0 = pw + (size_t)grow * 1536 + hh * 64 + c4;
        float4 bb = *(const float4*)(bq + hh * 64 + c4);
        float q0v = bb.x, q1v = bb.y, q2v = bb.z, q3v = bb.w;
#pragma unroll
        for (int z = 0; z < 4; ++z) {
            float4 a = *(const float4*)(q0 + (size_t)z * 786432);
            q0v += a.x; q1v += a.y; q2v += a.z; q3v += a.w;
        }
        Qs[rid][c4 + 0] = q0v;
        Qs[rid][c4 + 1] = q1v;
        Qs[rid][c4 + 2] = q2v;
        Qs[rid][c4 + 3] = q3v;
    }
    __syncthreads();
    {
        int j = tid & 127, th = tid >> 7;
        float acc[8] = {0.f, 0.f, 0.f, 0.f, 0.f, 0.f, 0.f, 0.f};
        for (int d0 = 0; d0 < 64; d0 += 4) {
            float4 kv = *(const float4*)&Ks[j * 68 + d0];
#pragma unroll
            for (int r = 0; r < 8; ++r) {
                float4 qv = *(const float4*)&Qs[th * 8 + r][d0];
                acc[r] += qv.x * kv.x + qv.y * kv.y + qv.z * kv.z + qv.w * kv.w;
            }
        }
        const float* tsr = tsym + ((size_t)b << 14) + (size_t)(tt * 16 + th * 8) * 128 + j;
#pragma unroll
        for (int r = 0; r < 8; ++r) {
            int t = th * 8 + r;
            float sv = (tsr[r * 128] > 0.f) ? acc[r] * 0.125f : -INFINITY;
            Ss[t * 132 + j] = sv;
        }
    }
    __syncthreads();
    {
        int row = tid >> 4, l16 = tid & 15;
        float v[8]; float m = -INFINITY;
#pragma unroll
        for (int c = 0; c < 8; ++c) { v[c] = Ss[row * 132 + l16 + c * 16]; m = fmaxf(m, v[c]); }
#pragma unroll
        for (int off = 8; off; off >>= 1) m = fmaxf(m, __shfl_xor(m, off));
        float ssum = 0.f;
#pragma unroll
        for (int c = 0; c < 8; ++c) {
            float e = (v[c] == -INFINITY) ? 0.f : __expf(v[c] - m);
            v[c] = e; ssum += e;
        }
#pragma unroll
        for (int off = 8; off; off >>= 1) ssum += __shfl_xor(ssum, off);
        float inv = 1.0f / (ssum + 1e-12f);
#pragma unroll
        for (int c = 0; c < 8; ++c) Ss[row * 132 + l16 + c * 16] = v[c] * inv;
    }
    __syncthreads();
    {
        int d = tid & 63, tq = tid >> 6;
        float a0 = 0.f, a1 = 0.f, a2 = 0.f, a3 = 0.f;
        for (int j0 = 0; j0 < 128; j0 += 4) {
            float4 vv = *(const float4*)&Vt[d * 132 + j0];
            float4 s0 = *(const float4*)&Ss[(tq * 4 + 0) * 132 + j0];
            float4 s1 = *(const float4*)&Ss[(tq * 4 + 1) * 132 + j0];
            float4 s2 = *(const float4*)&Ss[(tq * 4 + 2) * 132 + j0];
            float4 s3 = *(const float4*)&Ss[(tq * 4 + 3) * 132 + j0];
            a0 += s0.x * vv.x + s0.y * vv.y + s0.z * vv.z + s0.w * vv.w;
            a1 += s1.x * vv.x + s1.y * vv.y + s1.z * vv.z + s1.w * vv.w;
            a2 += s2.x * vv.x + s2.y * vv.y + s2.z * vv.z + s2.w * vv.w;
            a3 += s3.x * vv.x + s3.y * vv.y + s3.z * vv.z + s3.w * vv.w;
        }
        float accv[4] = {a0, a1, a2, a3};
        int growbase = b * 128 + tt * 16;
#pragma unroll
        for (int i = 0; i < 4; ++i) {
            int t = tq * 4 + i;
            agg16[(size_t)(growbase + t) * 512 + hh * 64 + d] = f2h(accv[i]);
        }
    }
}

// ---------------- aebe reduce (inline concat bias) ----------------
__global__ __launch_bounds__(256) void redae_k(const float* __restrict__ part,
                                               const float* __restrict__ eb1,
                                               float* __restrict__ aebe) {
    int idx = blockIdx.x * 256 + threadIdx.x;   // 512*128
    int col = idx & 127;
    float v = col < 64 ? eb1[col] : 0.0f;
#pragma unroll
    for (int z = 0; z < 4; ++z) v += part[(size_t)z * 65536 + idx];
    aebe[idx] = v;
}

// ---------------- dense cross-term GEMM (fp16): C3[b,i,j,o] = ((x[b,i]*x[b,j]) @ W1c)[o] ----------------
__global__ __launch_bounds__(256) void cross_k(const float* __restrict__ x,
                                               const u16* __restrict__ ect,
                                               float* __restrict__ C3) {
    int i = blockIdx.x, b = blockIdx.y;
    __shared__ float xis[512];
    __shared__ u16 As[2][128][32];   // [buf][row j][32 fp16], slot ^= ((row>>1)&3)
    int tid = threadIdx.x;
    {
        const float* xip = x + (size_t)(b * 128 + i) * 512;
        xis[tid] = xip[tid];
        xis[tid + 256] = xip[tid + 256];
    }
    int r = tid >> 1, half = tid & 1, koff = half * 16;
    const float* xr = x + (size_t)(b * 128 + r) * 512 + koff;
    int sw_r = (r >> 1) & 3;
    int lane = tid & 63, w = tid >> 6;
    int m0 = (w & 1) * 64, n0 = (w >> 1) * 32;
    int l15 = lane & 15, lsl = lane >> 4, kf = lsl * 8;
    const u16* pB0 = ect + (size_t)(n0 + l15) * 512 + kf;
    const u16* pB1 = ect + (size_t)(n0 + 16 + l15) * 512 + kf;
    f32x4 acc[4][2] = {};

    auto stageA = [&](int buf, int kbase) {
        float4 v0 = *(const float4*)(xr + kbase);
        float4 v1 = *(const float4*)(xr + kbase + 4);
        float4 v2 = *(const float4*)(xr + kbase + 8);
        float4 v3 = *(const float4*)(xr + kbase + 12);
        float xv[16] = {v0.x, v0.y, v0.z, v0.w, v1.x, v1.y, v1.z, v1.w,
                        v2.x, v2.y, v2.z, v2.w, v3.x, v3.y, v3.z, v3.w};
        short8 h0, h1;
#pragma unroll
        for (int q = 0; q < 8; ++q)
            h0[q] = (short)f2h(xv[q] * xis[kbase + koff + q]);
#pragma unroll
        for (int q = 0; q < 8; ++q)
            h1[q] = (short)f2h(xv[8 + q] * xis[kbase + koff + 8 + q]);
        *(short8*)&As[buf][r][((2 * half + 0) ^ sw_r) * 8] = h0;
        *(short8*)&As[buf][r][((2 * half + 1) ^ sw_r) * 8] = h1;
    };
    auto computeC = [&](int buf, int kbase) {
        f16x8 b0 = *(const f16x8*)(pB0 + kbase);
        f16x8 b1 = *(const f16x8*)(pB1 + kbase);
#pragma unroll
        for (int mf = 0; mf < 4; ++mf) {
            int rA = m0 + mf * 16 + l15;
            f16x8 ah = *(const f16x8*)&As[buf][rA][(lsl ^ ((rA >> 1) & 3)) * 8];
            acc[mf][0] = __builtin_amdgcn_mfma_f32_16x16x32_f16(ah, b0, acc[mf][0], 0, 0, 0);
            acc[mf][1] = __builtin_amdgcn_mfma_f32_16x16x32_f16(ah, b1, acc[mf][1], 0, 0, 0);
        }
    };

    __syncthreads();           // xis ready
    stageA(0, 0);
    __syncthreads();
    for (int s = 0; s < 16; ++s) {
        if (s < 15) stageA((s + 1) & 1, (s + 1) * 32);
        computeC(s & 1, s * 32);
        __syncthreads();
    }

    float* outp = C3 + (size_t)(b * 128 + i) * 128 * 64;
#pragma unroll
    for (int mf = 0; mf < 4; ++mf)
#pragma unroll
        for (int nf = 0; nf < 2; ++nf)
#pragma unroll
            for (int q = 0; q < 4; ++q)
                outp[(size_t)(m0 + mf * 16 + lsl * 4 + q) * 64 + (n0 + nf * 16 + l15)] = acc[mf][nf][q];
}

// ---------------- per-edge finish: gelu(C3+ae+be) -> layer2 -> layer3 -> sigmoid ----------------
__global__ __launch_bounds__(256) void efin_k(const int* __restrict__ ei, int E,
                                              const float* __restrict__ C3,
                                              const float* __restrict__ aebe,
                                              const float* __restrict__ ew2, const float* __restrict__ eb2,
                                              const float* __restrict__ ew3, const float* __restrict__ eb3,
                                              float* __restrict__ P) {
    __shared__ float G1[32][66];
    __shared__ float G2[32][66];
    __shared__ int s_src[32], s_dst[32];
    int tid = threadIdx.x;
    int e0 = blockIdx.x * 32;
    if (tid < 32) {
        int e = e0 + tid;
        s_src[tid] = e < E ? ei[e] : 0;
        s_dst[tid] = e < E ? ei[E + e] : 0;
    }
    __syncthreads();
    {
        int e = tid >> 3, c8 = (tid & 7) * 8;
        int s = s_src[e], d = s_dst[e];
        int bB = s >> 7, i2 = s & 127, j2 = d & 127;
        const float* c3 = C3 + ((size_t)(bB * 128 + i2) * 128 + j2) * 64 + c8;
        const float* ap = aebe + (size_t)s * 128 + c8;
        const float* bp = aebe + (size_t)d * 128 + 64 + c8;
#pragma unroll
        for (int q = 0; q < 8; ++q)
            G1[e][c8 + q] = gelu_f(c3[q] + ap[q] + bp[q]);
    }
    __syncthreads();
    {
        int col = tid & 63, eq = tid >> 6;
        float acc[8];
#pragma unroll
        for (int i = 0; i < 8; ++i) acc[i] = eb2[col];
        for (int m = 0; m < 64; ++m) {
            float wv = ew2[m * 64 + col];
#pragma unroll
            for (int i = 0; i < 8; ++i) acc[i] += G1[eq * 8 + i][m] * wv;
        }
#pragma unroll
        for (int i = 0; i < 8; ++i) G2[eq * 8 + i][col] = gelu_f(acc[i]);
    }
    __syncthreads();
    {
        int el2 = tid >> 3, c8 = (tid & 7) * 8;
        float p = 0.f;
#pragma unroll
        for (int i = 0; i < 8; ++i) p += G2[el2][c8 + i] * ew3[c8 + i];
        p += __shfl_xor(p, 1); p += __shfl_xor(p, 2); p += __shfl_xor(p, 4);
        if ((tid & 7) == 0 && e0 + el2 < E) {
            float logit = p + eb3[0];
            int s = s_src[el2], d2 = s_dst[el2];
            int bB = s >> 7, i2 = s & 127, j2 = d2 & 127;
            P[(bB << 14) + (i2 << 7) + j2] = 1.0f / (1.0f + expf(-logit));
        }
    }
}

// ---------------- final symmetrize + mask ----------------
__global__ __launch_bounds__(256) void final_k(const float* __restrict__ tsym,
                                               const float* __restrict__ P,
                                               float* __restrict__ out) {
    int idx = blockIdx.x * 256 + threadIdx.x;
    int b = idx >> 14, i = (idx >> 7) & 127, j = idx & 127;
    float o = 0.0f;
    if (i != j && tsym[idx] > 0.0f)
        o = 0.5f * (P[idx] + P[(b << 14) + (j << 7) + i]);
    out[idx] = o;
}

extern "C" void kernel_launch(void* const* d_in, const int* in_sizes, int n_in,
                              void* d_out, int out_size, void* d_ws, size_t ws_size,
                              hipStream_t stream) {
    const float* topo   = (const float*)d_in[0];
    const float* weight = (const float*)d_in[1];
    const int*   ei     = (const int*)d_in[2];
    const float* w_topo = (const float*)d_in[3];
    const float* b_topo = (const float*)d_in[4];
    const float* w_w    = (const float*)d_in[5];
    const float* b_w    = (const float*)d_in[6];
    const float* n_emb  = (const float*)d_in[7];
    const float* wq = (const float*)d_in[8];  const float* bq = (const float*)d_in[9];
    const float* wk = (const float*)d_in[10]; const float* bk = (const float*)d_in[11];
    const float* wv = (const float*)d_in[12]; const float* bv = (const float*)d_in[13];
    const float* wo = (const float*)d_in[14]; const float* bo = (const float*)d_in[15];
    const float* w1 = (const float*)d_in[16]; const float* b1 = (const float*)d_in[17];
    const float* w2 = (const float*)d_in[18]; const float* b2 = (const float*)d_in[19];
    const float* ew1 = (const float*)d_in[20]; const float* eb1 = (const float*)d_in[21];
    const float* ew2 = (const float*)d_in[22]; const float* eb2 = (const float*)d_in[23];
    const float* ew3 = (const float*)d_in[24]; const float* eb3 = (const float*)d_in[25];
    const int E = in_sizes[2] / 2;

    char* base = (char*)d_ws;
    size_t off = 0;
    auto alloc = [&](size_t bytes) { char* p = base + off; off += (bytes + 255) & ~(size_t)255; return p; };
    u16* qkvt = (u16*)alloc(3145728 * 2);
    u16* wot  = (u16*)alloc(1048576 * 2);
    u16* w1t  = (u16*)alloc(4194304 * 2);
    u16* w2t  = (u16*)alloc(4194304 * 2);
    u16* eabt = (u16*)alloc(65536 * 2);
    u16* ect  = (u16*)alloc(32768 * 2);
    u16* h16   = (u16*)alloc(262144 * 2);
    u16* agg16 = (u16*)alloc(262144 * 2);
    u16* mid16 = (u16*)alloc(1048576 * 2);
    u16* x16   = (u16*)alloc(262144 * 2);
    float* tsym  = (float*)alloc(65536 * 4);
    float* x     = (float*)alloc(262144 * 4);
    float* aebe  = (float*)alloc(65536 * 4);
    float* P     = (float*)alloc(65536 * 4);
    float* pw    = (float*)alloc(3145728 * 4);           // split-K partials (max: qkv 4x512x1536)
    float* C3    = (float*)alloc((size_t)16777216 * 4);  // dense cross term (B,N,N,64)

    prep_k<<<3096, 256, 0, stream>>>(wq, wk, wv, wo, w1, w2, ew1,
                                     qkvt, wot, w1t, w2t, eabt, ect);
    x0row_k<<<512, 256, 0, stream>>>(topo, weight, w_topo, b_topo, w_w, b_w, n_emb,
                                     tsym, x, h16);

    for (int d = 0; d < 4; ++d) {
        // QKV: split-K x4 -> partials; bias+reduce fused into attn
        gemm2<128, true, false, false, false, false, false><<<dim3(24, 8, 4), 256, 0, stream>>>(
            h16, qkvt + (size_t)d * 1536 * 512,
            nullptr, nullptr, nullptr, nullptr, pw, 512, 1536);
        attn_k<<<dim3(8, 8, 4), 256, 0, stream>>>(pw, bq + d * 512, bk + d * 512, bv + d * 512,
                                                  tsym, agg16);
        // WO: split-K x8 -> partials -> fused reduce+res+LN
        gemm2<64, true, false, false, false, false, false><<<dim3(8, 8, 8), 256, 0, stream>>>(
            agg16, wot + (size_t)d * 512 * 512,
            nullptr, nullptr, nullptr, nullptr, pw, 512, 512);
        redln_k<8, true, false><<<512, 256, 0, stream>>>(pw, bo + d * 512, x, h16);
        // MLP1: split-K x2 -> partials -> fused reduce+bias+gelu -> mid16
        gemm2<256, true, false, false, false, false, false><<<dim3(32, 8, 2), 256, 0, stream>>>(
            h16, w1t + (size_t)d * 2048 * 512,
            nullptr, nullptr, nullptr, nullptr, pw, 512, 2048);
        redg_k<<<512, 256, 0, stream>>>(pw, b1 + d * 2048, mid16);
        // MLP2: split-K x8 -> partials -> fused reduce+res (+LN | +fp16)
        gemm2<256, true, false, false, false, false, false><<<dim3(8, 8, 8), 256, 0, stream>>>(
            mid16, w2t + (size_t)d * 512 * 2048,
            nullptr, nullptr, nullptr, nullptr, pw, 2048, 512);
        if (d < 3) {
            redln_k<8, true, false><<<512, 256, 0, stream>>>(pw, b2 + d * 512, x, h16);
        } else {
            redln_k<8, false, true><<<512, 256, 0, stream>>>(pw, b2 + d * 512, x, x16);
        }
    }

    // edge-final MLP: aebe via split-K x4 + reduce; dense cross GEMM; per-edge finish
    gemm2<128, true, false, false, false, false, false><<<dim3(2, 8, 4), 256, 0, stream>>>(
        x16, eabt, nullptr, nullptr, nullptr, nullptr, pw, 512, 128);
    redae_k<<<256, 256, 0, stream>>>(pw, eb1, aebe);
    cross_k<<<dim3(128, 4), 256, 0, stream>>>(x, ect, C3);
    efin_k<<<(E + 31) / 32, 256, 0, stream>>>(ei, E, C3, aebe, ew2, eb2, ew3, eb3, P);
    final_k<<<256, 256, 0, stream>>>(tsym, P, (float*)d_out);
}

// Round 14
// 256.935 us; speedup vs baseline: 4.3501x; 1.7426x over previous
//
#include <hip/hip_runtime.h>
#include <hip/hip_bf16.h>
#include <math.h>

typedef __attribute__((ext_vector_type(8))) _Float16 f16x8;
typedef __attribute__((ext_vector_type(8))) short short8;
typedef __attribute__((ext_vector_type(4))) float f32x4;
typedef unsigned short u16;

__device__ __forceinline__ float gelu_f(float x) {
    float x3 = x * x * x;
    return 0.5f * x * (1.0f + tanhf(0.7978845608028654f * (x + 0.044715f * x3)));
}
__device__ __forceinline__ u16 f2h(float v) {
    _Float16 h = (_Float16)v;
    return *(u16*)&h;
}
__device__ __forceinline__ float h2f(u16 u) {
    _Float16 h = *(_Float16*)&u;
    return (float)h;
}

// ---------------- fused tsym + x0 + LN (+ tsym store), one row per block ----------------
__global__ __launch_bounds__(256) void x0row_k(const float* __restrict__ topo,
                                               const float* __restrict__ weight,
                                               const float* __restrict__ w_topo,
                                               const float* __restrict__ b_topo,
                                               const float* __restrict__ w_w,
                                               const float* __restrict__ b_w,
                                               const float* __restrict__ n_emb,
                                               float* __restrict__ tsym,
                                               float* __restrict__ x,
                                               u16* __restrict__ h16) {
    int bn = blockIdx.x;                 // 0..511
    int b = bn >> 7, n = bn & 127;
    int tid = threadIdx.x;
    __shared__ float tsr[128];
    __shared__ float red[256];
    if (tid < 128) {
        float v = topo[bn * 128 + tid] + topo[(b << 14) + (tid << 7) + n];
        tsr[tid] = v;
        tsym[bn * 128 + tid] = v;
    }
    __syncthreads();
    int c0 = tid, c1 = tid + 256;
    float acc0 = 0.f, acc1 = 0.f;
#pragma unroll 4
    for (int m = 0; m < 128; ++m) {
        float t = tsr[m];
        acc0 += t * w_topo[m * 512 + c0];
        acc1 += t * w_topo[m * 512 + c1];
    }
    float wgt = weight[bn];
    float v0 = acc0 + b_topo[c0] + wgt * w_w[c0] + b_w[c0] + n_emb[n * 512 + c0];
    float v1 = acc1 + b_topo[c1] + wgt * w_w[c1] + b_w[c1] + n_emb[n * 512 + c1];
    x[bn * 512 + c0] = v0;
    x[bn * 512 + c1] = v1;
    red[tid] = v0 + v1;
    __syncthreads();
    for (int off = 128; off > 0; off >>= 1) { if (tid < off) red[tid] += red[tid + off]; __syncthreads(); }
    float mean = red[0] * (1.0f / 512.0f);
    __syncthreads();
    float d0 = v0 - mean, d1 = v1 - mean;
    red[tid] = d0 * d0 + d1 * d1;
    __syncthreads();
    for (int off = 128; off > 0; off >>= 1) { if (tid < off) red[tid] += red[tid + off]; __syncthreads(); }
    float rs = rsqrtf(red[0] * (1.0f / 512.0f) + 1e-6f);
    h16[bn * 512 + c0] = f2h(d0 * rs);
    h16[bn * 512 + c1] = f2h(d1 * rs);
}

// ---------------- weight transpose + fp16 prep ----------------
__global__ __launch_bounds__(256) void prep_k(
    const float* __restrict__ wq, const float* __restrict__ wk, const float* __restrict__ wv,
    const float* __restrict__ wo, const float* __restrict__ w1, const float* __restrict__ w2,
    const float* __restrict__ ew1,
    u16* __restrict__ qkvt, u16* __restrict__ wot,
    u16* __restrict__ w1t, u16* __restrict__ w2t,
    u16* __restrict__ eabt, u16* __restrict__ ect) {
    __shared__ u16 Hs[64][68];
    int bid = blockIdx.x;
    int region, tr, KK;
    u16* dh;
    if (bid < 768)       { region = 0; tr = bid;        KK = 512;  dh = qkvt; }
    else if (bid < 1024) { region = 1; tr = bid - 768;  KK = 512;  dh = wot; }
    else if (bid < 2048) { region = 2; tr = bid - 1024; KK = 512;  dh = w1t; }
    else if (bid < 3072) { region = 3; tr = bid - 2048; KK = 2048; dh = w2t; }
    else if (bid < 3088) { region = 4; tr = bid - 3072; KK = 512;  dh = eabt; }
    else                 { region = 5; tr = bid - 3088; KK = 512;  dh = ect; }
    int ktiles = KK >> 6;
    int tn = tr / ktiles, tk = tr % ktiles;
    int k0 = tk * 64, n0g = tn * 64;
    int tid = threadIdx.x;
#pragma unroll
    for (int p = 0; p < 4; ++p) {
        int kk = p * 16 + (tid >> 4);
        int nn = (tid & 15) * 4;
        int kg = k0 + kk, ng = n0g + nn;
        const float* src;
        if (region == 0) {
            int d = ng / 1536; int nr = ng - d * 1536; int sel = nr >> 9; int nc = nr & 511;
            const float* w = sel == 0 ? wq : (sel == 1 ? wk : wv);
            src = w + ((size_t)(d * 512 + kg)) * 512 + nc;
        } else if (region == 1) {
            int d = ng >> 9; int nc = ng & 511;
            src = wo + ((size_t)(d * 512 + kg)) * 512 + nc;
        } else if (region == 2) {
            int d = ng >> 11; int nc = ng & 2047;
            src = w1 + ((size_t)(d * 512 + kg)) * 2048 + nc;
        } else if (region == 3) {
            int d = ng >> 9; int nc = ng & 511;
            src = w2 + ((size_t)(d * 2048 + kg)) * 512 + nc;
        } else if (region == 4) {
            src = (ng < 64) ? (ew1 + (size_t)kg * 64 + ng) : (ew1 + (size_t)(512 + kg) * 64 + (ng - 64));
        } else {
            src = ew1 + (size_t)(1024 + kg) * 64 + ng;
        }
        float4 v = *(const float4*)src;
        *(ushort4*)&Hs[kk][nn] = make_ushort4(f2h(v.x), f2h(v.y), f2h(v.z), f2h(v.w));
    }
    __syncthreads();
#pragma unroll
    for (int p = 0; p < 2; ++p) {
        int chunk = p * 256 + tid;
        int nl = chunk >> 3;
        int k8 = (chunk & 7) * 8;
        ushort4 ha, hb;
        ha.x = Hs[k8 + 0][nl]; ha.y = Hs[k8 + 1][nl]; ha.z = Hs[k8 + 2][nl]; ha.w = Hs[k8 + 3][nl];
        hb.x = Hs[k8 + 4][nl]; hb.y = Hs[k8 + 5][nl]; hb.z = Hs[k8 + 6][nl]; hb.w = Hs[k8 + 7][nl];
        size_t dst = (size_t)(n0g + nl) * KK + k0 + k8;
        *(ushort4*)(dh + dst) = ha; *(ushort4*)(dh + dst + 4) = hb;
    }
}

// ---------------- LDS-staged double-buffered fp16 MFMA GEMM ----------------
template <int KC, bool PARTIAL, bool GELU, bool RES, bool OUTF, bool OUTS, bool EBIAS>
__global__ __launch_bounds__(256) void gemm2(
    const u16* __restrict__ A16, const u16* __restrict__ W16,
    const float* __restrict__ bias, const float* __restrict__ Rres,
    float* __restrict__ C, u16* __restrict__ C16,
    float* __restrict__ part, int lda, int N) {
    __shared__ u16 sbuf[2][2][64][32];  // [buf][A/B][row][32 fp16]
    const int tid = threadIdx.x;
    const int l = tid & 63;
    const int w = tid >> 6;
    const int bn0 = blockIdx.x * 64;
    const int bm0 = blockIdx.y * 64;
    const int z = blockIdx.z;

    const u16* gp[2];
#pragma unroll
    for (int i = 0; i < 2; ++i) {
        int o = (i * 4 + w) * 1024 + l * 16;
        int mat = o >> 12;               // 0 = A, 1 = B
        int r = (o >> 6) & 63;
        int slot = (o >> 4) & 3;
        int lslot = slot ^ ((r >> 1) & 3);
        int kel = lslot * 8;
        const u16* basep = mat == 0 ? (A16 + (size_t)(bm0 + r) * lda)
                                    : (W16 + (size_t)(bn0 + r) * lda);
        gp[i] = basep + kel + z * KC;
    }

    f32x4 acc[2][2] = {};
    constexpr int S = KC / 32;

    auto stage = [&](int buf, int ko) {
#pragma unroll
        for (int i = 0; i < 2; ++i) {
            __builtin_amdgcn_global_load_lds(
                (const __attribute__((address_space(1))) void*)(gp[i] + ko),
                (__attribute__((address_space(3))) void*)((char*)&sbuf[buf][0][0][0] + (i * 4 + w) * 1024),
                16, 0, 0);
        }
    };
    auto compute = [&](int buf) {
        f16x8 a[2], b[2];
        int l15 = l & 15, lsl = l >> 4;
        int rA0 = (w & 1) * 32 + l15;
        int rB0 = (w >> 1) * 32 + l15;
#pragma unroll
        for (int f = 0; f < 2; ++f) {
            int rA = rA0 + f * 16;
            int rB = rB0 + f * 16;
            a[f] = *(const f16x8*)&sbuf[buf][0][rA][(lsl ^ ((rA >> 1) & 3)) * 8];
            b[f] = *(const f16x8*)&sbuf[buf][1][rB][(lsl ^ ((rB >> 1) & 3)) * 8];
        }
#pragma unroll
        for (int fm = 0; fm < 2; ++fm)
#pragma unroll
            for (int fn = 0; fn < 2; ++fn)
                acc[fm][fn] = __builtin_amdgcn_mfma_f32_16x16x32_f16(a[fm], b[fn], acc[fm][fn], 0, 0, 0);
    };

    stage(0, 0);
    __syncthreads();
#pragma unroll
    for (int s = 0; s < S; ++s) {
        if (s + 1 < S) stage((s + 1) & 1, (s + 1) * 32);
        compute(s & 1);
        __syncthreads();
    }

    int rb = bm0 + (w & 1) * 32 + ((l >> 4)) * 4;
    int cb = bn0 + (w >> 1) * 32 + (l & 15);
#pragma unroll
    for (int fm = 0; fm < 2; ++fm)
#pragma unroll
        for (int fn = 0; fn < 2; ++fn) {
            int col = cb + fn * 16;
            float bv;
            if (PARTIAL) bv = 0.f;
            else if (EBIAS) bv = col < 64 ? bias[col] : 0.f;
            else bv = bias[col];
#pragma unroll
            for (int r = 0; r < 4; ++r) {
                int row = rb + fm * 16 + r;
                float v = acc[fm][fn][r] + bv;
                if (PARTIAL) {
                    part[(size_t)z * 512 * N + (size_t)row * N + col] = v;
                } else {
                    if (GELU) v = gelu_f(v);
                    if (RES) v += Rres[(size_t)row * N + col];
                    if (OUTF) C[(size_t)row * N + col] = v;
                    if (OUTS) C16[(size_t)row * N + col] = f2h(v);
                }
            }
        }
}

// ---------------- split-K reduce + bias + residual -> x, then LN (or raw fp16) ----------------
template <int NZ, bool DOLN, bool DOSPLITX>
__global__ __launch_bounds__(256) void redln_k(const float* __restrict__ part,
                                               const float* __restrict__ bias,
                                               float* __restrict__ x,
                                               u16* __restrict__ h16) {
    int row = blockIdx.x;
    int tid = threadIdx.x;
    int c0 = tid, c1 = tid + 256;
    float v0 = bias[c0], v1 = bias[c1];
#pragma unroll
    for (int z = 0; z < NZ; ++z) {
        v0 += part[(size_t)z * 262144 + row * 512 + c0];
        v1 += part[(size_t)z * 262144 + row * 512 + c1];
    }
    v0 += x[row * 512 + c0];
    v1 += x[row * 512 + c1];
    x[row * 512 + c0] = v0;
    x[row * 512 + c1] = v1;
    if (DOSPLITX) {
        h16[row * 512 + c0] = f2h(v0);
        h16[row * 512 + c1] = f2h(v1);
    }
    if (DOLN) {
        __shared__ float red[256];
        red[tid] = v0 + v1;
        __syncthreads();
        for (int off = 128; off > 0; off >>= 1) { if (tid < off) red[tid] += red[tid + off]; __syncthreads(); }
        float mean = red[0] * (1.0f / 512.0f);
        __syncthreads();
        float d0 = v0 - mean, d1 = v1 - mean;
        red[tid] = d0 * d0 + d1 * d1;
        __syncthreads();
        for (int off = 128; off > 0; off >>= 1) { if (tid < off) red[tid] += red[tid + off]; __syncthreads(); }
        float rs = rsqrtf(red[0] * (1.0f / 512.0f) + 1e-6f);
        h16[row * 512 + c0] = f2h(d0 * rs);
        h16[row * 512 + c1] = f2h(d1 * rs);
    }
}

// ---------------- QKV 2-slice reduce + bias -> fp16 qkv (1.5 MB, L2-resident) ----------------
__global__ __launch_bounds__(256) void redqkv_k(const float* __restrict__ part,
                                                const float* __restrict__ bq,
                                                const float* __restrict__ bk,
                                                const float* __restrict__ bv,
                                                u16* __restrict__ qkv16) {
    int row = blockIdx.x;       // 0..511
    int tid = threadIdx.x;
#pragma unroll
    for (int u = 0; u < 6; ++u) {
        int col = tid + u * 256;
        float bias = col < 512 ? bq[col] : (col < 1024 ? bk[col - 512] : bv[col - 1024]);
        float v = bias + part[(size_t)row * 1536 + col]
                + part[(size_t)786432 + row * 1536 + col];
        qkv16[(size_t)row * 1536 + col] = f2h(v);
    }
}

// ---------------- fused masked attention; reads fp16 qkv ----------------
__global__ __launch_bounds__(256) void attn_k(const u16* __restrict__ qkv16,
                                              const float* __restrict__ tsym,
                                              u16* __restrict__ agg16) {
    int tt = blockIdx.x, hh = blockIdx.y, b = blockIdx.z;
    __shared__ __align__(16) float Ks[128 * 68];
    __shared__ __align__(16) float Vt[64 * 132];
    __shared__ __align__(16) float Ss[16 * 132];
    __shared__ __align__(16) float Qs[16][68];
    int tid = threadIdx.x;
    {
        int j = tid >> 1, c0 = (tid & 1) * 32;
        const u16* kr = qkv16 + (size_t)(b * 128 + j) * 1536 + 512 + hh * 64 + c0;
        const u16* vr = kr + 512;
#pragma unroll
        for (int c = 0; c < 32; c += 8) {
            f16x8 kv = *(const f16x8*)(kr + c);
            f16x8 vv = *(const f16x8*)(vr + c);
#pragma unroll
            for (int q = 0; q < 8; ++q) {
                Ks[j * 68 + c0 + c + q] = (float)kv[q];
                Vt[(c0 + c + q) * 132 + j] = (float)vv[q];
            }
        }
    }
    {
        int rid = tid >> 4, c4 = (tid & 15) * 4;
        int grow = b * 128 + tt * 16 + rid;
        const u16* q0 = qkv16 + (size_t)grow * 1536 + hh * 64 + c4;
        Qs[rid][c4 + 0] = h2f(q0[0]);
        Qs[rid][c4 + 1] = h2f(q0[1]);
        Qs[rid][c4 + 2] = h2f(q0[2]);
        Qs[rid][c4 + 3] = h2f(q0[3]);
    }
    __syncthreads();
    {
        int j = tid & 127, th = tid >> 7;
        float acc[8] = {0.f, 0.f, 0.f, 0.f, 0.f, 0.f, 0.f, 0.f};
        for (int d0 = 0; d0 < 64; d0 += 4) {
            float4 kv = *(const float4*)&Ks[j * 68 + d0];
#pragma unroll
            for (int r = 0; r < 8; ++r) {
                float4 qv = *(const float4*)&Qs[th * 8 + r][d0];
                acc[r] += qv.x * kv.x + qv.y * kv.y + qv.z * kv.z + qv.w * kv.w;
            }
        }
        const float* tsr = tsym + ((size_t)b << 14) + (size_t)(tt * 16 + th * 8) * 128 + j;
#pragma unroll
        for (int r = 0; r < 8; ++r) {
            int t = th * 8 + r;
            float sv = (tsr[r * 128] > 0.f) ? acc[r] * 0.125f : -INFINITY;
            Ss[t * 132 + j] = sv;
        }
    }
    __syncthreads();
    {
        int row = tid >> 4, l16 = tid & 15;
        float v[8]; float m = -INFINITY;
#pragma unroll
        for (int c = 0; c < 8; ++c) { v[c] = Ss[row * 132 + l16 + c * 16]; m = fmaxf(m, v[c]); }
#pragma unroll
        for (int off = 8; off; off >>= 1) m = fmaxf(m, __shfl_xor(m, off));
        float ssum = 0.f;
#pragma unroll
        for (int c = 0; c < 8; ++c) {
            float e = (v[c] == -INFINITY) ? 0.f : __expf(v[c] - m);
            v[c] = e; ssum += e;
        }
#pragma unroll
        for (int off = 8; off; off >>= 1) ssum += __shfl_xor(ssum, off);
        float inv = 1.0f / (ssum + 1e-12f);
#pragma unroll
        for (int c = 0; c < 8; ++c) Ss[row * 132 + l16 + c * 16] = v[c] * inv;
    }
    __syncthreads();
    {
        int d = tid & 63, tq = tid >> 6;
        float a0 = 0.f, a1 = 0.f, a2 = 0.f, a3 = 0.f;
        for (int j0 = 0; j0 < 128; j0 += 4) {
            float4 vv = *(const float4*)&Vt[d * 132 + j0];
            float4 s0 = *(const float4*)&Ss[(tq * 4 + 0) * 132 + j0];
            float4 s1 = *(const float4*)&Ss[(tq * 4 + 1) * 132 + j0];
            float4 s2 = *(const float4*)&Ss[(tq * 4 + 2) * 132 + j0];
            float4 s3 = *(const float4*)&Ss[(tq * 4 + 3) * 132 + j0];
            a0 += s0.x * vv.x + s0.y * vv.y + s0.z * vv.z + s0.w * vv.w;
            a1 += s1.x * vv.x + s1.y * vv.y + s1.z * vv.z + s1.w * vv.w;
            a2 += s2.x * vv.x + s2.y * vv.y + s2.z * vv.z + s2.w * vv.w;
            a3 += s3.x * vv.x + s3.y * vv.y + s3.z * vv.z + s3.w * vv.w;
        }
        float accv[4] = {a0, a1, a2, a3};
        int growbase = b * 128 + tt * 16;
#pragma unroll
        for (int i = 0; i < 4; ++i) {
            int t = tq * 4 + i;
            agg16[(size_t)(growbase + t) * 512 + hh * 64 + d] = f2h(accv[i]);
        }
    }
}

// ---------------- aebe reduce (inline concat bias) ----------------
__global__ __launch_bounds__(256) void redae_k(const float* __restrict__ part,
                                               const float* __restrict__ eb1,
                                               float* __restrict__ aebe) {
    int idx = blockIdx.x * 256 + threadIdx.x;   // 512*128
    int col = idx & 127;
    float v = col < 64 ? eb1[col] : 0.0f;
#pragma unroll
    for (int z = 0; z < 4; ++z) v += part[(size_t)z * 65536 + idx];
    aebe[idx] = v;
}

// ---------------- dense cross-term GEMM (fp16): C3[b,i,j,o] = ((x[b,i]*x[b,j]) @ W1c)[o] ----------------
__global__ __launch_bounds__(256) void cross_k(const float* __restrict__ x,
                                               const u16* __restrict__ ect,
                                               float* __restrict__ C3) {
    int i = blockIdx.x, b = blockIdx.y;
    __shared__ float xis[512];
    __shared__ u16 As[2][128][32];   // [buf][row j][32 fp16], slot ^= ((row>>1)&3)
    int tid = threadIdx.x;
    {
        const float* xip = x + (size_t)(b * 128 + i) * 512;
        xis[tid] = xip[tid];
        xis[tid + 256] = xip[tid + 256];
    }
    int r = tid >> 1, half = tid & 1, koff = half * 16;
    const float* xr = x + (size_t)(b * 128 + r) * 512 + koff;
    int sw_r = (r >> 1) & 3;
    int lane = tid & 63, w = tid >> 6;
    int m0 = (w & 1) * 64, n0 = (w >> 1) * 32;
    int l15 = lane & 15, lsl = lane >> 4, kf = lsl * 8;
    const u16* pB0 = ect + (size_t)(n0 + l15) * 512 + kf;
    const u16* pB1 = ect + (size_t)(n0 + 16 + l15) * 512 + kf;
    f32x4 acc[4][2] = {};

    auto stageA = [&](int buf, int kbase) {
        float4 v0 = *(const float4*)(xr + kbase);
        float4 v1 = *(const float4*)(xr + kbase + 4);
        float4 v2 = *(const float4*)(xr + kbase + 8);
        float4 v3 = *(const float4*)(xr + kbase + 12);
        float xv[16] = {v0.x, v0.y, v0.z, v0.w, v1.x, v1.y, v1.z, v1.w,
                        v2.x, v2.y, v2.z, v2.w, v3.x, v3.y, v3.z, v3.w};
        short8 h0, h1;
#pragma unroll
        for (int q = 0; q < 8; ++q)
            h0[q] = (short)f2h(xv[q] * xis[kbase + koff + q]);
#pragma unroll
        for (int q = 0; q < 8; ++q)
            h1[q] = (short)f2h(xv[8 + q] * xis[kbase + koff + 8 + q]);
        *(short8*)&As[buf][r][((2 * half + 0) ^ sw_r) * 8] = h0;
        *(short8*)&As[buf][r][((2 * half + 1) ^ sw_r) * 8] = h1;
    };
    auto computeC = [&](int buf, int kbase) {
        f16x8 b0 = *(const f16x8*)(pB0 + kbase);
        f16x8 b1 = *(const f16x8*)(pB1 + kbase);
#pragma unroll
        for (int mf = 0; mf < 4; ++mf) {
            int rA = m0 + mf * 16 + l15;
            f16x8 ah = *(const f16x8*)&As[buf][rA][(lsl ^ ((rA >> 1) & 3)) * 8];
            acc[mf][0] = __builtin_amdgcn_mfma_f32_16x16x32_f16(ah, b0, acc[mf][0], 0, 0, 0);
            acc[mf][1] = __builtin_amdgcn_mfma_f32_16x16x32_f16(ah, b1, acc[mf][1], 0, 0, 0);
        }
    };

    __syncthreads();           // xis ready
    stageA(0, 0);
    __syncthreads();
    for (int s = 0; s < 16; ++s) {
        if (s < 15) stageA((s + 1) & 1, (s + 1) * 32);
        computeC(s & 1, s * 32);
        __syncthreads();
    }

    float* outp = C3 + (size_t)(b * 128 + i) * 128 * 64;
#pragma unroll
    for (int mf = 0; mf < 4; ++mf)
#pragma unroll
        for (int nf = 0; nf < 2; ++nf)
#pragma unroll
            for (int q = 0; q < 4; ++q)
                outp[(size_t)(m0 + mf * 16 + lsl * 4 + q) * 64 + (n0 + nf * 16 + l15)] = acc[mf][nf][q];
}

// ---------------- per-edge finish: gelu(C3+ae+be) -> layer2 -> layer3 -> sigmoid ----------------
__global__ __launch_bounds__(256) void efin_k(const int* __restrict__ ei, int E,
                                              const float* __restrict__ C3,
                                              const float* __restrict__ aebe,
                                              const float* __restrict__ ew2, const float* __restrict__ eb2,
                                              const float* __restrict__ ew3, const float* __restrict__ eb3,
                                              float* __restrict__ P) {
    __shared__ float G1[32][66];
    __shared__ float G2[32][66];
    __shared__ int s_src[32], s_dst[32];
    int tid = threadIdx.x;
    int e0 = blockIdx.x * 32;
    if (tid < 32) {
        int e = e0 + tid;
        s_src[tid] = e < E ? ei[e] : 0;
        s_dst[tid] = e < E ? ei[E + e] : 0;
    }
    __syncthreads();
    {
        int e = tid >> 3, c8 = (tid & 7) * 8;
        int s = s_src[e], d = s_dst[e];
        int bB = s >> 7, i2 = s & 127, j2 = d & 127;
        const float* c3 = C3 + ((size_t)(bB * 128 + i2) * 128 + j2) * 64 + c8;
        const float* ap = aebe + (size_t)s * 128 + c8;
        const float* bp = aebe + (size_t)d * 128 + 64 + c8;
#pragma unroll
        for (int q = 0; q < 8; ++q)
            G1[e][c8 + q] = gelu_f(c3[q] + ap[q] + bp[q]);
    }
    __syncthreads();
    {
        int col = tid & 63, eq = tid >> 6;
        float acc[8];
#pragma unroll
        for (int i = 0; i < 8; ++i) acc[i] = eb2[col];
        for (int m = 0; m < 64; ++m) {
            float wv = ew2[m * 64 + col];
#pragma unroll
            for (int i = 0; i < 8; ++i) acc[i] += G1[eq * 8 + i][m] * wv;
        }
#pragma unroll
        for (int i = 0; i < 8; ++i) G2[eq * 8 + i][col] = gelu_f(acc[i]);
    }
    __syncthreads();
    {
        int el2 = tid >> 3, c8 = (tid & 7) * 8;
        float p = 0.f;
#pragma unroll
        for (int i = 0; i < 8; ++i) p += G2[el2][c8 + i] * ew3[c8 + i];
        p += __shfl_xor(p, 1); p += __shfl_xor(p, 2); p += __shfl_xor(p, 4);
        if ((tid & 7) == 0 && e0 + el2 < E) {
            float logit = p + eb3[0];
            int s = s_src[el2], d2 = s_dst[el2];
            int bB = s >> 7, i2 = s & 127, j2 = d2 & 127;
            P[(bB << 14) + (i2 << 7) + j2] = 1.0f / (1.0f + expf(-logit));
        }
    }
}

// ---------------- final symmetrize + mask ----------------
__global__ __launch_bounds__(256) void final_k(const float* __restrict__ tsym,
                                               const float* __restrict__ P,
                                               float* __restrict__ out) {
    int idx = blockIdx.x * 256 + threadIdx.x;
    int b = idx >> 14, i = (idx >> 7) & 127, j = idx & 127;
    float o = 0.0f;
    if (i != j && tsym[idx] > 0.0f)
        o = 0.5f * (P[idx] + P[(b << 14) + (j << 7) + i]);
    out[idx] = o;
}

extern "C" void kernel_launch(void* const* d_in, const int* in_sizes, int n_in,
                              void* d_out, int out_size, void* d_ws, size_t ws_size,
                              hipStream_t stream) {
    const float* topo   = (const float*)d_in[0];
    const float* weight = (const float*)d_in[1];
    const int*   ei     = (const int*)d_in[2];
    const float* w_topo = (const float*)d_in[3];
    const float* b_topo = (const float*)d_in[4];
    const float* w_w    = (const float*)d_in[5];
    const float* b_w    = (const float*)d_in[6];
    const float* n_emb  = (const float*)d_in[7];
    const float* wq = (const float*)d_in[8];  const float* bq = (const float*)d_in[9];
    const float* wk = (const float*)d_in[10]; const float* bk = (const float*)d_in[11];
    const float* wv = (const float*)d_in[12]; const float* bv = (const float*)d_in[13];
    const float* wo = (const float*)d_in[14]; const float* bo = (const float*)d_in[15];
    const float* w1 = (const float*)d_in[16]; const float* b1 = (const float*)d_in[17];
    const float* w2 = (const float*)d_in[18]; const float* b2 = (const float*)d_in[19];
    const float* ew1 = (const float*)d_in[20]; const float* eb1 = (const float*)d_in[21];
    const float* ew2 = (const float*)d_in[22]; const float* eb2 = (const float*)d_in[23];
    const float* ew3 = (const float*)d_in[24]; const float* eb3 = (const float*)d_in[25];
    const int E = in_sizes[2] / 2;

    char* base = (char*)d_ws;
    size_t off = 0;
    auto alloc = [&](size_t bytes) { char* p = base + off; off += (bytes + 255) & ~(size_t)255; return p; };
    u16* qkvt = (u16*)alloc(3145728 * 2);
    u16* wot  = (u16*)alloc(1048576 * 2);
    u16* w1t  = (u16*)alloc(4194304 * 2);
    u16* w2t  = (u16*)alloc(4194304 * 2);
    u16* eabt = (u16*)alloc(65536 * 2);
    u16* ect  = (u16*)alloc(32768 * 2);
    u16* h16   = (u16*)alloc(262144 * 2);
    u16* agg16 = (u16*)alloc(262144 * 2);
    u16* mid16 = (u16*)alloc(1048576 * 2);
    u16* x16   = (u16*)alloc(262144 * 2);
    u16* qkv16 = (u16*)alloc(786432 * 2);
    float* tsym  = (float*)alloc(65536 * 4);
    float* x     = (float*)alloc(262144 * 4);
    float* aebe  = (float*)alloc(65536 * 4);
    float* P     = (float*)alloc(65536 * 4);
    float* pw    = (float*)alloc(1572864 * 4);           // split-K partials (max: qkv 2x512x1536)
    float* C3    = (float*)alloc((size_t)16777216 * 4);  // dense cross term (B,N,N,64)

    prep_k<<<3096, 256, 0, stream>>>(wq, wk, wv, wo, w1, w2, ew1,
                                     qkvt, wot, w1t, w2t, eabt, ect);
    x0row_k<<<512, 256, 0, stream>>>(topo, weight, w_topo, b_topo, w_w, b_w, n_emb,
                                     tsym, x, h16);

    for (int d = 0; d < 4; ++d) {
        // QKV: split-K x2 -> partials -> fp16 qkv (L2-resident) -> attn
        gemm2<256, true, false, false, false, false, false><<<dim3(24, 8, 2), 256, 0, stream>>>(
            h16, qkvt + (size_t)d * 1536 * 512,
            nullptr, nullptr, nullptr, nullptr, pw, 512, 1536);
        redqkv_k<<<512, 256, 0, stream>>>(pw, bq + d * 512, bk + d * 512, bv + d * 512, qkv16);
        attn_k<<<dim3(8, 8, 4), 256, 0, stream>>>(qkv16, tsym, agg16);
        // WO: split-K x4 -> partials -> fused reduce+res+LN
        gemm2<128, true, false, false, false, false, false><<<dim3(8, 8, 4), 256, 0, stream>>>(
            agg16, wot + (size_t)d * 512 * 512,
            nullptr, nullptr, nullptr, nullptr, pw, 512, 512);
        redln_k<4, true, false><<<512, 256, 0, stream>>>(pw, bo + d * 512, x, h16);
        // MLP1: full-K, gelu + fp16 out
        gemm2<512, false, true, false, false, true, false><<<dim3(32, 8, 1), 256, 0, stream>>>(
            h16, w1t + (size_t)d * 2048 * 512,
            b1 + d * 2048, nullptr, nullptr, mid16, nullptr, 512, 2048);
        // MLP2: split-K x4 -> partials -> fused reduce+res (+LN | +fp16)
        gemm2<512, true, false, false, false, false, false><<<dim3(8, 8, 4), 256, 0, stream>>>(
            mid16, w2t + (size_t)d * 512 * 2048,
            nullptr, nullptr, nullptr, nullptr, pw, 2048, 512);
        if (d < 3) {
            redln_k<4, true, false><<<512, 256, 0, stream>>>(pw, b2 + d * 512, x, h16);
        } else {
            redln_k<4, false, true><<<512, 256, 0, stream>>>(pw, b2 + d * 512, x, x16);
        }
    }

    // edge-final MLP: aebe via split-K x4 + reduce; dense cross GEMM; per-edge finish
    gemm2<128, true, false, false, false, false, false><<<dim3(2, 8, 4), 256, 0, stream>>>(
        x16, eabt, nullptr, nullptr, nullptr, nullptr, pw, 512, 128);
    redae_k<<<256, 256, 0, stream>>>(pw, eb1, aebe);
    cross_k<<<dim3(128, 4), 256, 0, stream>>>(x, ect, C3);
    efin_k<<<(E + 31) / 32, 256, 0, stream>>>(ei, E, C3, aebe, ew2, eb2, ew3, eb3, P);
    final_k<<<256, 256, 0, stream>>>(tsym, P, (float*)d_out);
}

// Round 15
// 248.420 us; speedup vs baseline: 4.4992x; 1.0343x over previous
//
#include <hip/hip_runtime.h>
#include <hip/hip_bf16.h>
#include <math.h>

typedef __attribute__((ext_vector_type(8))) _Float16 f16x8;
typedef __attribute__((ext_vector_type(8))) short short8;
typedef __attribute__((ext_vector_type(4))) float f32x4;
typedef unsigned short u16;

__device__ __forceinline__ float gelu_f(float x) {
    float x3 = x * x * x;
    return 0.5f * x * (1.0f + tanhf(0.7978845608028654f * (x + 0.044715f * x3)));
}
__device__ __forceinline__ u16 f2h(float v) {
    _Float16 h = (_Float16)v;
    return *(u16*)&h;
}
__device__ __forceinline__ float h2f(u16 u) {
    _Float16 h = *(_Float16*)&u;
    return (float)h;
}

// ---------------- fused weight-prep + x0row (grid 3608: 0..3095 weights, 3096+ x0 rows) ----------------
__global__ __launch_bounds__(256) void prep_k(
    const float* __restrict__ wq, const float* __restrict__ wk, const float* __restrict__ wv,
    const float* __restrict__ wo, const float* __restrict__ w1, const float* __restrict__ w2,
    const float* __restrict__ ew1,
    u16* __restrict__ qkvt, u16* __restrict__ wot,
    u16* __restrict__ w1t, u16* __restrict__ w2t,
    u16* __restrict__ eabt, u16* __restrict__ ect,
    const float* __restrict__ topo, const float* __restrict__ weight,
    const float* __restrict__ w_topo, const float* __restrict__ b_topo,
    const float* __restrict__ w_w, const float* __restrict__ b_w,
    const float* __restrict__ n_emb,
    float* __restrict__ tsym, float* __restrict__ x, u16* __restrict__ h16) {
    __shared__ u16 Hs[64][68];
    __shared__ float tsr[128];
    __shared__ float red[256];
    int bid = blockIdx.x;
    int tid = threadIdx.x;

    if (bid >= 3096) {
        // ---- x0row path ----
        int bn = bid - 3096;             // 0..511
        int b = bn >> 7, n = bn & 127;
        if (tid < 128) {
            float v = topo[bn * 128 + tid] + topo[(b << 14) + (tid << 7) + n];
            tsr[tid] = v;
            tsym[bn * 128 + tid] = v;
        }
        __syncthreads();
        int c0 = tid, c1 = tid + 256;
        float acc0 = 0.f, acc1 = 0.f;
#pragma unroll 4
        for (int m = 0; m < 128; ++m) {
            float t = tsr[m];
            acc0 += t * w_topo[m * 512 + c0];
            acc1 += t * w_topo[m * 512 + c1];
        }
        float wgt = weight[bn];
        float v0 = acc0 + b_topo[c0] + wgt * w_w[c0] + b_w[c0] + n_emb[n * 512 + c0];
        float v1 = acc1 + b_topo[c1] + wgt * w_w[c1] + b_w[c1] + n_emb[n * 512 + c1];
        x[bn * 512 + c0] = v0;
        x[bn * 512 + c1] = v1;
        red[tid] = v0 + v1;
        __syncthreads();
        for (int off = 128; off > 0; off >>= 1) { if (tid < off) red[tid] += red[tid + off]; __syncthreads(); }
        float mean = red[0] * (1.0f / 512.0f);
        __syncthreads();
        float d0 = v0 - mean, d1 = v1 - mean;
        red[tid] = d0 * d0 + d1 * d1;
        __syncthreads();
        for (int off = 128; off > 0; off >>= 1) { if (tid < off) red[tid] += red[tid + off]; __syncthreads(); }
        float rs = rsqrtf(red[0] * (1.0f / 512.0f) + 1e-6f);
        h16[bn * 512 + c0] = f2h(d0 * rs);
        h16[bn * 512 + c1] = f2h(d1 * rs);
        return;
    }

    // ---- weight prep path ----
    int region, tr, KK;
    u16* dh;
    if (bid < 768)       { region = 0; tr = bid;        KK = 512;  dh = qkvt; }
    else if (bid < 1024) { region = 1; tr = bid - 768;  KK = 512;  dh = wot; }
    else if (bid < 2048) { region = 2; tr = bid - 1024; KK = 512;  dh = w1t; }
    else if (bid < 3072) { region = 3; tr = bid - 2048; KK = 2048; dh = w2t; }
    else if (bid < 3088) { region = 4; tr = bid - 3072; KK = 512;  dh = eabt; }
    else                 { region = 5; tr = bid - 3088; KK = 512;  dh = ect; }
    int ktiles = KK >> 6;
    int tn = tr / ktiles, tk = tr % ktiles;
    int k0 = tk * 64, n0g = tn * 64;
#pragma unroll
    for (int p = 0; p < 4; ++p) {
        int kk = p * 16 + (tid >> 4);
        int nn = (tid & 15) * 4;
        int kg = k0 + kk, ng = n0g + nn;
        const float* src;
        if (region == 0) {
            int d = ng / 1536; int nr = ng - d * 1536; int sel = nr >> 9; int nc = nr & 511;
            const float* w = sel == 0 ? wq : (sel == 1 ? wk : wv);
            src = w + ((size_t)(d * 512 + kg)) * 512 + nc;
        } else if (region == 1) {
            int d = ng >> 9; int nc = ng & 511;
            src = wo + ((size_t)(d * 512 + kg)) * 512 + nc;
        } else if (region == 2) {
            int d = ng >> 11; int nc = ng & 2047;
            src = w1 + ((size_t)(d * 512 + kg)) * 2048 + nc;
        } else if (region == 3) {
            int d = ng >> 9; int nc = ng & 511;
            src = w2 + ((size_t)(d * 2048 + kg)) * 512 + nc;
        } else if (region == 4) {
            src = (ng < 64) ? (ew1 + (size_t)kg * 64 + ng) : (ew1 + (size_t)(512 + kg) * 64 + (ng - 64));
        } else {
            src = ew1 + (size_t)(1024 + kg) * 64 + ng;
        }
        float4 v = *(const float4*)src;
        *(ushort4*)&Hs[kk][nn] = make_ushort4(f2h(v.x), f2h(v.y), f2h(v.z), f2h(v.w));
    }
    __syncthreads();
#pragma unroll
    for (int p = 0; p < 2; ++p) {
        int chunk = p * 256 + tid;
        int nl = chunk >> 3;
        int k8 = (chunk & 7) * 8;
        ushort4 ha, hb;
        ha.x = Hs[k8 + 0][nl]; ha.y = Hs[k8 + 1][nl]; ha.z = Hs[k8 + 2][nl]; ha.w = Hs[k8 + 3][nl];
        hb.x = Hs[k8 + 4][nl]; hb.y = Hs[k8 + 5][nl]; hb.z = Hs[k8 + 6][nl]; hb.w = Hs[k8 + 7][nl];
        size_t dst = (size_t)(n0g + nl) * KK + k0 + k8;
        *(ushort4*)(dh + dst) = ha; *(ushort4*)(dh + dst + 4) = hb;
    }
}

// ---------------- LDS-staged double-buffered fp16 MFMA GEMM ----------------
template <int KC, bool PARTIAL, bool GELU, bool RES, bool OUTF, bool OUTS, bool EBIAS>
__global__ __launch_bounds__(256) void gemm2(
    const u16* __restrict__ A16, const u16* __restrict__ W16,
    const float* __restrict__ bias, const float* __restrict__ Rres,
    float* __restrict__ C, u16* __restrict__ C16,
    float* __restrict__ part, int lda, int N) {
    __shared__ u16 sbuf[2][2][64][32];  // [buf][A/B][row][32 fp16]
    const int tid = threadIdx.x;
    const int l = tid & 63;
    const int w = tid >> 6;
    const int bn0 = blockIdx.x * 64;
    const int bm0 = blockIdx.y * 64;
    const int z = blockIdx.z;

    const u16* gp[2];
#pragma unroll
    for (int i = 0; i < 2; ++i) {
        int o = (i * 4 + w) * 1024 + l * 16;
        int mat = o >> 12;               // 0 = A, 1 = B
        int r = (o >> 6) & 63;
        int slot = (o >> 4) & 3;
        int lslot = slot ^ ((r >> 1) & 3);
        int kel = lslot * 8;
        const u16* basep = mat == 0 ? (A16 + (size_t)(bm0 + r) * lda)
                                    : (W16 + (size_t)(bn0 + r) * lda);
        gp[i] = basep + kel + z * KC;
    }

    f32x4 acc[2][2] = {};
    constexpr int S = KC / 32;

    auto stage = [&](int buf, int ko) {
#pragma unroll
        for (int i = 0; i < 2; ++i) {
            __builtin_amdgcn_global_load_lds(
                (const __attribute__((address_space(1))) void*)(gp[i] + ko),
                (__attribute__((address_space(3))) void*)((char*)&sbuf[buf][0][0][0] + (i * 4 + w) * 1024),
                16, 0, 0);
        }
    };
    auto compute = [&](int buf) {
        f16x8 a[2], b[2];
        int l15 = l & 15, lsl = l >> 4;
        int rA0 = (w & 1) * 32 + l15;
        int rB0 = (w >> 1) * 32 + l15;
#pragma unroll
        for (int f = 0; f < 2; ++f) {
            int rA = rA0 + f * 16;
            int rB = rB0 + f * 16;
            a[f] = *(const f16x8*)&sbuf[buf][0][rA][(lsl ^ ((rA >> 1) & 3)) * 8];
            b[f] = *(const f16x8*)&sbuf[buf][1][rB][(lsl ^ ((rB >> 1) & 3)) * 8];
        }
#pragma unroll
        for (int fm = 0; fm < 2; ++fm)
#pragma unroll
            for (int fn = 0; fn < 2; ++fn)
                acc[fm][fn] = __builtin_amdgcn_mfma_f32_16x16x32_f16(a[fm], b[fn], acc[fm][fn], 0, 0, 0);
    };

    stage(0, 0);
    __syncthreads();
#pragma unroll
    for (int s = 0; s < S; ++s) {
        if (s + 1 < S) stage((s + 1) & 1, (s + 1) * 32);
        compute(s & 1);
        __syncthreads();
    }

    int rb = bm0 + (w & 1) * 32 + ((l >> 4)) * 4;
    int cb = bn0 + (w >> 1) * 32 + (l & 15);
#pragma unroll
    for (int fm = 0; fm < 2; ++fm)
#pragma unroll
        for (int fn = 0; fn < 2; ++fn) {
            int col = cb + fn * 16;
            float bv;
            if (PARTIAL) bv = 0.f;
            else if (EBIAS) bv = col < 64 ? bias[col] : 0.f;
            else bv = bias[col];
#pragma unroll
            for (int r = 0; r < 4; ++r) {
                int row = rb + fm * 16 + r;
                float v = acc[fm][fn][r] + bv;
                if (PARTIAL) {
                    part[(size_t)z * 512 * N + (size_t)row * N + col] = v;
                } else {
                    if (GELU) v = gelu_f(v);
                    if (RES) v += Rres[(size_t)row * N + col];
                    if (OUTF) C[(size_t)row * N + col] = v;
                    if (OUTS) C16[(size_t)row * N + col] = f2h(v);
                }
            }
        }
}

// ---------------- split-K reduce + bias + residual -> x, then LN (or raw fp16) ----------------
template <int NZ, bool DOLN, bool DOSPLITX>
__global__ __launch_bounds__(256) void redln_k(const float* __restrict__ part,
                                               const float* __restrict__ bias,
                                               float* __restrict__ x,
                                               u16* __restrict__ h16) {
    int row = blockIdx.x;
    int tid = threadIdx.x;
    int c0 = tid, c1 = tid + 256;
    float v0 = bias[c0], v1 = bias[c1];
#pragma unroll
    for (int z = 0; z < NZ; ++z) {
        v0 += part[(size_t)z * 262144 + row * 512 + c0];
        v1 += part[(size_t)z * 262144 + row * 512 + c1];
    }
    v0 += x[row * 512 + c0];
    v1 += x[row * 512 + c1];
    x[row * 512 + c0] = v0;
    x[row * 512 + c1] = v1;
    if (DOSPLITX) {
        h16[row * 512 + c0] = f2h(v0);
        h16[row * 512 + c1] = f2h(v1);
    }
    if (DOLN) {
        __shared__ float red[256];
        red[tid] = v0 + v1;
        __syncthreads();
        for (int off = 128; off > 0; off >>= 1) { if (tid < off) red[tid] += red[tid + off]; __syncthreads(); }
        float mean = red[0] * (1.0f / 512.0f);
        __syncthreads();
        float d0 = v0 - mean, d1 = v1 - mean;
        red[tid] = d0 * d0 + d1 * d1;
        __syncthreads();
        for (int off = 128; off > 0; off >>= 1) { if (tid < off) red[tid] += red[tid + off]; __syncthreads(); }
        float rs = rsqrtf(red[0] * (1.0f / 512.0f) + 1e-6f);
        h16[row * 512 + c0] = f2h(d0 * rs);
        h16[row * 512 + c1] = f2h(d1 * rs);
    }
}

// ---------------- QKV 2-slice reduce + bias -> fp16 qkv (1.5 MB, L2-resident) ----------------
__global__ __launch_bounds__(256) void redqkv_k(const float* __restrict__ part,
                                                const float* __restrict__ bq,
                                                const float* __restrict__ bk,
                                                const float* __restrict__ bv,
                                                u16* __restrict__ qkv16) {
    int row = blockIdx.x;       // 0..511
    int tid = threadIdx.x;
#pragma unroll
    for (int u = 0; u < 6; ++u) {
        int col = tid + u * 256;
        float bias = col < 512 ? bq[col] : (col < 1024 ? bk[col - 512] : bv[col - 1024]);
        float v = bias + part[(size_t)row * 1536 + col]
                + part[(size_t)786432 + row * 1536 + col];
        qkv16[(size_t)row * 1536 + col] = f2h(v);
    }
}

// ---------------- fused masked attention; reads fp16 qkv ----------------
__global__ __launch_bounds__(256) void attn_k(const u16* __restrict__ qkv16,
                                              const float* __restrict__ tsym,
                                              u16* __restrict__ agg16) {
    int tt = blockIdx.x, hh = blockIdx.y, b = blockIdx.z;
    __shared__ __align__(16) float Ks[128 * 68];
    __shared__ __align__(16) float Vt[64 * 132];
    __shared__ __align__(16) float Ss[16 * 132];
    __shared__ __align__(16) float Qs[16][68];
    int tid = threadIdx.x;
    {
        int j = tid >> 1, c0 = (tid & 1) * 32;
        const u16* kr = qkv16 + (size_t)(b * 128 + j) * 1536 + 512 + hh * 64 + c0;
        const u16* vr = kr + 512;
#pragma unroll
        for (int c = 0; c < 32; c += 8) {
            f16x8 kv = *(const f16x8*)(kr + c);
            f16x8 vv = *(const f16x8*)(vr + c);
#pragma unroll
            for (int q = 0; q < 8; ++q) {
                Ks[j * 68 + c0 + c + q] = (float)kv[q];
                Vt[(c0 + c + q) * 132 + j] = (float)vv[q];
            }
        }
    }
    {
        int rid = tid >> 4, c4 = (tid & 15) * 4;
        int grow = b * 128 + tt * 16 + rid;
        const u16* q0 = qkv16 + (size_t)grow * 1536 + hh * 64 + c4;
        Qs[rid][c4 + 0] = h2f(q0[0]);
        Qs[rid][c4 + 1] = h2f(q0[1]);
        Qs[rid][c4 + 2] = h2f(q0[2]);
        Qs[rid][c4 + 3] = h2f(q0[3]);
    }
    __syncthreads();
    {
        int j = tid & 127, th = tid >> 7;
        float acc[8] = {0.f, 0.f, 0.f, 0.f, 0.f, 0.f, 0.f, 0.f};
        for (int d0 = 0; d0 < 64; d0 += 4) {
            float4 kv = *(const float4*)&Ks[j * 68 + d0];
#pragma unroll
            for (int r = 0; r < 8; ++r) {
                float4 qv = *(const float4*)&Qs[th * 8 + r][d0];
                acc[r] += qv.x * kv.x + qv.y * kv.y + qv.z * kv.z + qv.w * kv.w;
            }
        }
        const float* tsr = tsym + ((size_t)b << 14) + (size_t)(tt * 16 + th * 8) * 128 + j;
#pragma unroll
        for (int r = 0; r < 8; ++r) {
            int t = th * 8 + r;
            float sv = (tsr[r * 128] > 0.f) ? acc[r] * 0.125f : -INFINITY;
            Ss[t * 132 + j] = sv;
        }
    }
    __syncthreads();
    {
        int row = tid >> 4, l16 = tid & 15;
        float v[8]; float m = -INFINITY;
#pragma unroll
        for (int c = 0; c < 8; ++c) { v[c] = Ss[row * 132 + l16 + c * 16]; m = fmaxf(m, v[c]); }
#pragma unroll
        for (int off = 8; off; off >>= 1) m = fmaxf(m, __shfl_xor(m, off));
        float ssum = 0.f;
#pragma unroll
        for (int c = 0; c < 8; ++c) {
            float e = (v[c] == -INFINITY) ? 0.f : __expf(v[c] - m);
            v[c] = e; ssum += e;
        }
#pragma unroll
        for (int off = 8; off; off >>= 1) ssum += __shfl_xor(ssum, off);
        float inv = 1.0f / (ssum + 1e-12f);
#pragma unroll
        for (int c = 0; c < 8; ++c) Ss[row * 132 + l16 + c * 16] = v[c] * inv;
    }
    __syncthreads();
    {
        int d = tid & 63, tq = tid >> 6;
        float a0 = 0.f, a1 = 0.f, a2 = 0.f, a3 = 0.f;
        for (int j0 = 0; j0 < 128; j0 += 4) {
            float4 vv = *(const float4*)&Vt[d * 132 + j0];
            float4 s0 = *(const float4*)&Ss[(tq * 4 + 0) * 132 + j0];
            float4 s1 = *(const float4*)&Ss[(tq * 4 + 1) * 132 + j0];
            float4 s2 = *(const float4*)&Ss[(tq * 4 + 2) * 132 + j0];
            float4 s3 = *(const float4*)&Ss[(tq * 4 + 3) * 132 + j0];
            a0 += s0.x * vv.x + s0.y * vv.y + s0.z * vv.z + s0.w * vv.w;
            a1 += s1.x * vv.x + s1.y * vv.y + s1.z * vv.z + s1.w * vv.w;
            a2 += s2.x * vv.x + s2.y * vv.y + s2.z * vv.z + s2.w * vv.w;
            a3 += s3.x * vv.x + s3.y * vv.y + s3.z * vv.z + s3.w * vv.w;
        }
        float accv[4] = {a0, a1, a2, a3};
        int growbase = b * 128 + tt * 16;
#pragma unroll
        for (int i = 0; i < 4; ++i) {
            int t = tq * 4 + i;
            agg16[(size_t)(growbase + t) * 512 + hh * 64 + d] = f2h(accv[i]);
        }
    }
}

// ---------------- aebe reduce (inline concat bias) ----------------
__global__ __launch_bounds__(256) void redae_k(const float* __restrict__ part,
                                               const float* __restrict__ eb1,
                                               float* __restrict__ aebe) {
    int idx = blockIdx.x * 256 + threadIdx.x;   // 512*128
    int col = idx & 127;
    float v = col < 64 ? eb1[col] : 0.0f;
#pragma unroll
    for (int z = 0; z < 4; ++z) v += part[(size_t)z * 65536 + idx];
    aebe[idx] = v;
}

// ---------------- dense cross-term GEMM (fp16 out): C3[b,i,j,o] = ((x[b,i]*x[b,j]) @ W1c)[o] ----------------
__global__ __launch_bounds__(256) void cross_k(const float* __restrict__ x,
                                               const u16* __restrict__ ect,
                                               u16* __restrict__ C3) {
    int i = blockIdx.x, b = blockIdx.y;
    __shared__ float xis[512];
    __shared__ u16 As[2][128][32];   // [buf][row j][32 fp16], slot ^= ((row>>1)&3)
    int tid = threadIdx.x;
    {
        const float* xip = x + (size_t)(b * 128 + i) * 512;
        xis[tid] = xip[tid];
        xis[tid + 256] = xip[tid + 256];
    }
    int r = tid >> 1, half = tid & 1, koff = half * 16;
    const float* xr = x + (size_t)(b * 128 + r) * 512 + koff;
    int sw_r = (r >> 1) & 3;
    int lane = tid & 63, w = tid >> 6;
    int m0 = (w & 1) * 64, n0 = (w >> 1) * 32;
    int l15 = lane & 15, lsl = lane >> 4, kf = lsl * 8;
    const u16* pB0 = ect + (size_t)(n0 + l15) * 512 + kf;
    const u16* pB1 = ect + (size_t)(n0 + 16 + l15) * 512 + kf;
    f32x4 acc[4][2] = {};

    auto stageA = [&](int buf, int kbase) {
        float4 v0 = *(const float4*)(xr + kbase);
        float4 v1 = *(const float4*)(xr + kbase + 4);
        float4 v2 = *(const float4*)(xr + kbase + 8);
        float4 v3 = *(const float4*)(xr + kbase + 12);
        float xv[16] = {v0.x, v0.y, v0.z, v0.w, v1.x, v1.y, v1.z, v1.w,
                        v2.x, v2.y, v2.z, v2.w, v3.x, v3.y, v3.z, v3.w};
        short8 h0, h1;
#pragma unroll
        for (int q = 0; q < 8; ++q)
            h0[q] = (short)f2h(xv[q] * xis[kbase + koff + q]);
#pragma unroll
        for (int q = 0; q < 8; ++q)
            h1[q] = (short)f2h(xv[8 + q] * xis[kbase + koff + 8 + q]);
        *(short8*)&As[buf][r][((2 * half + 0) ^ sw_r) * 8] = h0;
        *(short8*)&As[buf][r][((2 * half + 1) ^ sw_r) * 8] = h1;
    };
    auto computeC = [&](int buf, int kbase) {
        f16x8 b0 = *(const f16x8*)(pB0 + kbase);
        f16x8 b1 = *(const f16x8*)(pB1 + kbase);
#pragma unroll
        for (int mf = 0; mf < 4; ++mf) {
            int rA = m0 + mf * 16 + l15;
            f16x8 ah = *(const f16x8*)&As[buf][rA][(lsl ^ ((rA >> 1) & 3)) * 8];
            acc[mf][0] = __builtin_amdgcn_mfma_f32_16x16x32_f16(ah, b0, acc[mf][0], 0, 0, 0);
            acc[mf][1] = __builtin_amdgcn_mfma_f32_16x16x32_f16(ah, b1, acc[mf][1], 0, 0, 0);
        }
    };

    __syncthreads();           // xis ready
    stageA(0, 0);
    __syncthreads();
    for (int s = 0; s < 16; ++s) {
        if (s < 15) stageA((s + 1) & 1, (s + 1) * 32);
        computeC(s & 1, s * 32);
        __syncthreads();
    }

    u16* outp = C3 + (size_t)(b * 128 + i) * 128 * 64;
#pragma unroll
    for (int mf = 0; mf < 4; ++mf)
#pragma unroll
        for (int nf = 0; nf < 2; ++nf)
#pragma unroll
            for (int q = 0; q < 4; ++q)
                outp[(size_t)(m0 + mf * 16 + lsl * 4 + q) * 64 + (n0 + nf * 16 + l15)] =
                    f2h(acc[mf][nf][q]);
}

// ---------------- per-edge finish: gelu(C3+ae+be) -> layer2 -> layer3 -> sigmoid ----------------
__global__ __launch_bounds__(256) void efin_k(const int* __restrict__ ei, int E,
                                              const u16* __restrict__ C3,
                                              const float* __restrict__ aebe,
                                              const float* __restrict__ ew2, const float* __restrict__ eb2,
                                              const float* __restrict__ ew3, const float* __restrict__ eb3,
                                              float* __restrict__ P) {
    __shared__ float G1[32][66];
    __shared__ float G2[32][66];
    __shared__ int s_src[32], s_dst[32];
    int tid = threadIdx.x;
    int e0 = blockIdx.x * 32;
    if (tid < 32) {
        int e = e0 + tid;
        s_src[tid] = e < E ? ei[e] : 0;
        s_dst[tid] = e < E ? ei[E + e] : 0;
    }
    __syncthreads();
    {
        int e = tid >> 3, c8 = (tid & 7) * 8;
        int s = s_src[e], d = s_dst[e];
        int bB = s >> 7, i2 = s & 127, j2 = d & 127;
        const u16* c3 = C3 + ((size_t)(bB * 128 + i2) * 128 + j2) * 64 + c8;
        const float* ap = aebe + (size_t)s * 128 + c8;
        const float* bp = aebe + (size_t)d * 128 + 64 + c8;
        f16x8 cv = *(const f16x8*)c3;
#pragma unroll
        for (int q = 0; q < 8; ++q)
            G1[e][c8 + q] = gelu_f((float)cv[q] + ap[q] + bp[q]);
    }
    __syncthreads();
    {
        int col = tid & 63, eq = tid >> 6;
        float acc[8];
#pragma unroll
        for (int i = 0; i < 8; ++i) acc[i] = eb2[col];
        for (int m = 0; m < 64; ++m) {
            float wv = ew2[m * 64 + col];
#pragma unroll
            for (int i = 0; i < 8; ++i) acc[i] += G1[eq * 8 + i][m] * wv;
        }
#pragma unroll
        for (int i = 0; i < 8; ++i) G2[eq * 8 + i][col] = gelu_f(acc[i]);
    }
    __syncthreads();
    {
        int el2 = tid >> 3, c8 = (tid & 7) * 8;
        float p = 0.f;
#pragma unroll
        for (int i = 0; i < 8; ++i) p += G2[el2][c8 + i] * ew3[c8 + i];
        p += __shfl_xor(p, 1); p += __shfl_xor(p, 2); p += __shfl_xor(p, 4);
        if ((tid & 7) == 0 && e0 + el2 < E) {
            float logit = p + eb3[0];
            int s = s_src[el2], d2 = s_dst[el2];
            int bB = s >> 7, i2 = s & 127, j2 = d2 & 127;
            P[(bB << 14) + (i2 << 7) + j2] = 1.0f / (1.0f + expf(-logit));
        }
    }
}

// ---------------- final symmetrize + mask ----------------
__global__ __launch_bounds__(256) void final_k(const float* __restrict__ tsym,
                                               const float* __restrict__ P,
                                               float* __restrict__ out) {
    int idx = blockIdx.x * 256 + threadIdx.x;
    int b = idx >> 14, i = (idx >> 7) & 127, j = idx & 127;
    float o = 0.0f;
    if (i != j && tsym[idx] > 0.0f)
        o = 0.5f * (P[idx] + P[(b << 14) + (j << 7) + i]);
    out[idx] = o;
}

extern "C" void kernel_launch(void* const* d_in, const int* in_sizes, int n_in,
                              void* d_out, int out_size, void* d_ws, size_t ws_size,
                              hipStream_t stream) {
    const float* topo   = (const float*)d_in[0];
    const float* weight = (const float*)d_in[1];
    const int*   ei     = (const int*)d_in[2];
    const float* w_topo = (const float*)d_in[3];
    const float* b_topo = (const float*)d_in[4];
    const float* w_w    = (const float*)d_in[5];
    const float* b_w    = (const float*)d_in[6];
    const float* n_emb  = (const float*)d_in[7];
    const float* wq = (const float*)d_in[8];  const float* bq = (const float*)d_in[9];
    const float* wk = (const float*)d_in[10]; const float* bk = (const float*)d_in[11];
    const float* wv = (const float*)d_in[12]; const float* bv = (const float*)d_in[13];
    const float* wo = (const float*)d_in[14]; const float* bo = (const float*)d_in[15];
    const float* w1 = (const float*)d_in[16]; const float* b1 = (const float*)d_in[17];
    const float* w2 = (const float*)d_in[18]; const float* b2 = (const float*)d_in[19];
    const float* ew1 = (const float*)d_in[20]; const float* eb1 = (const float*)d_in[21];
    const float* ew2 = (const float*)d_in[22]; const float* eb2 = (const float*)d_in[23];
    const float* ew3 = (const float*)d_in[24]; const float* eb3 = (const float*)d_in[25];
    const int E = in_sizes[2] / 2;

    char* base = (char*)d_ws;
    size_t off = 0;
    auto alloc = [&](size_t bytes) { char* p = base + off; off += (bytes + 255) & ~(size_t)255; return p; };
    u16* qkvt = (u16*)alloc(3145728 * 2);
    u16* wot  = (u16*)alloc(1048576 * 2);
    u16* w1t  = (u16*)alloc(4194304 * 2);
    u16* w2t  = (u16*)alloc(4194304 * 2);
    u16* eabt = (u16*)alloc(65536 * 2);
    u16* ect  = (u16*)alloc(32768 * 2);
    u16* h16   = (u16*)alloc(262144 * 2);
    u16* agg16 = (u16*)alloc(262144 * 2);
    u16* mid16 = (u16*)alloc(1048576 * 2);
    u16* x16   = (u16*)alloc(262144 * 2);
    u16* qkv16 = (u16*)alloc(786432 * 2);
    u16* C3    = (u16*)alloc((size_t)16777216 * 2);      // dense cross term (B,N,N,64) fp16
    float* tsym  = (float*)alloc(65536 * 4);
    float* x     = (float*)alloc(262144 * 4);
    float* aebe  = (float*)alloc(65536 * 4);
    float* P     = (float*)alloc(65536 * 4);
    float* pw    = (float*)alloc(1572864 * 4);           // split-K partials (max: qkv 2x512x1536)

    prep_k<<<3608, 256, 0, stream>>>(wq, wk, wv, wo, w1, w2, ew1,
                                     qkvt, wot, w1t, w2t, eabt, ect,
                                     topo, weight, w_topo, b_topo, w_w, b_w, n_emb,
                                     tsym, x, h16);

    for (int d = 0; d < 4; ++d) {
        // QKV: split-K x2 -> partials -> fp16 qkv (L2-resident) -> attn
        gemm2<256, true, false, false, false, false, false><<<dim3(24, 8, 2), 256, 0, stream>>>(
            h16, qkvt + (size_t)d * 1536 * 512,
            nullptr, nullptr, nullptr, nullptr, pw, 512, 1536);
        redqkv_k<<<512, 256, 0, stream>>>(pw, bq + d * 512, bk + d * 512, bv + d * 512, qkv16);
        attn_k<<<dim3(8, 8, 4), 256, 0, stream>>>(qkv16, tsym, agg16);
        // WO: split-K x4 -> partials -> fused reduce+res+LN
        gemm2<128, true, false, false, false, false, false><<<dim3(8, 8, 4), 256, 0, stream>>>(
            agg16, wot + (size_t)d * 512 * 512,
            nullptr, nullptr, nullptr, nullptr, pw, 512, 512);
        redln_k<4, true, false><<<512, 256, 0, stream>>>(pw, bo + d * 512, x, h16);
        // MLP1: full-K, gelu + fp16 out
        gemm2<512, false, true, false, false, true, false><<<dim3(32, 8, 1), 256, 0, stream>>>(
            h16, w1t + (size_t)d * 2048 * 512,
            b1 + d * 2048, nullptr, nullptr, mid16, nullptr, 512, 2048);
        // MLP2: split-K x4 -> partials -> fused reduce+res (+LN | +fp16)
        gemm2<512, true, false, false, false, false, false><<<dim3(8, 8, 4), 256, 0, stream>>>(
            mid16, w2t + (size_t)d * 512 * 2048,
            nullptr, nullptr, nullptr, nullptr, pw, 2048, 512);
        if (d < 3) {
            redln_k<4, true, false><<<512, 256, 0, stream>>>(pw, b2 + d * 512, x, h16);
        } else {
            redln_k<4, false, true><<<512, 256, 0, stream>>>(pw, b2 + d * 512, x, x16);
        }
    }

    // edge-final MLP: aebe via split-K x4 + reduce; dense cross GEMM (fp16 out); per-edge finish
    gemm2<128, true, false, false, false, false, false><<<dim3(2, 8, 4), 256, 0, stream>>>(
        x16, eabt, nullptr, nullptr, nullptr, nullptr, pw, 512, 128);
    redae_k<<<256, 256, 0, stream>>>(pw, eb1, aebe);
    cross_k<<<dim3(128, 4), 256, 0, stream>>>(x, ect, C3);
    efin_k<<<(E + 31) / 32, 256, 0, stream>>>(ei, E, C3, aebe, ew2, eb2, ew3, eb3, P);
    final_k<<<256, 256, 0, stream>>>(tsym, P, (float*)d_out);
}